// Round 5
// baseline (3891.428 us; speedup 1.0000x reference)
//
#include <hip/hip_runtime.h>
#include <stdint.h>

// SUBNET_15290083574166: encoder MLP -> 256-step recurrent f MLP -> output h MLP
// B=4096, T=256, NX=128, NU=16, NY=16, NB=NA=32, H=256
//
// Precision (VERIFIED r4, absmax 0.0625 vs thr 0.24): f16 hi/lo pairs (2^-22)
// on all recurrence operands, 2-accum (hi + lo*2^-11); encoder bf16 pairs;
// hnet xf-pair x f16-single. DO NOT change the numerics.
//
// r5 perf changes (bit-identical math):
//  - launch_bounds(512,1): VGPR cap 256 so 184 weight VGPRs stay resident
//    (r4's (512,2) capped at 128 -> per-step weight reloads, MfmaUtil 19%)
//  - 3 barriers/step (was 6): u_t in regs, split h1/h2 buffers, xu[2] dbuf
//  - A-frags read once per kk (LDS b128 traffic 76 -> 48 per step/wave)
//  - W3-lo + W2-lo streamed from L2; W3-hi in LDS; rest in VGPRs

typedef __attribute__((ext_vector_type(8))) short s8v;      // 8 bf16 bits
typedef __attribute__((ext_vector_type(8))) _Float16 h8v;   // 8 f16
typedef __attribute__((ext_vector_type(4))) float f4v;

__device__ __forceinline__ f4v mfma16(s8v a, s8v b, f4v c) {
  return __builtin_amdgcn_mfma_f32_16x16x32_bf16(a, b, c, 0, 0, 0);
}
__device__ __forceinline__ f4v mfmaH(h8v a, h8v b, f4v c) {
  return __builtin_amdgcn_mfma_f32_16x16x32_f16(a, b, c, 0, 0, 0);
}
__device__ __forceinline__ f4v zero4() { return (f4v){0.f, 0.f, 0.f, 0.f}; }
__device__ __forceinline__ h8v zeroh8() {
  h8v z;
#pragma unroll
  for (int q = 0; q < 8; ++q) z[q] = (_Float16)0.f;
  return z;
}

__device__ __forceinline__ unsigned short f2b(float x) {  // f32->bf16 RNE
  unsigned int u = __builtin_bit_cast(unsigned int, x);
  u += 0x7fffu + ((u >> 16) & 1u);
  return (unsigned short)(u >> 16);
}
__device__ __forceinline__ float b2f(unsigned short h) {
  return __builtin_bit_cast(float, (unsigned int)h << 16);
}
__device__ __forceinline__ unsigned short f2h(float x) {
  return __builtin_bit_cast(unsigned short, (_Float16)x);
}
__device__ __forceinline__ float h2f(unsigned short h) {
  return (float)__builtin_bit_cast(_Float16, h);
}

__device__ __forceinline__ float tanhf_fast(float x) {
  x = fminf(15.f, fmaxf(-15.f, x));
  float e = __expf(2.f * x);
  return (e - 1.f) / (e + 1.f);
}

// ---------------- weight swizzle: fp32 [K][N] -> fragment order ---------------
// frag: idx(nt,kk,lane,j) = ((nt*KK + kk)*64 + lane)*8 + j
//   holds W[kk*32 + (lane>>4)*8 + j][nt*16 + (lane&15)]  (zero-pad k>=K)
// mode 0: bf16 hi at dst[dhi+local], bf16 lo at dst[dlo+local]
// mode 3: f16 hi at dst[dhi+local], f16((v-hi)*2048) at dst[dlo+local]
// mode 1: f16 at dst[dhi+local]
struct SwzDesc { const float* src; long woff; long dhi; long dlo; int K; int Kp; int N; int mode; };
struct SwzTable { SwzDesc d[12]; long tot_work; };

__global__ void swz_kernel(SwzTable tbl, unsigned short* __restrict__ dst) {
  long gid = (long)blockIdx.x * 256 + threadIdx.x;
  if (gid >= tbl.tot_work) return;
  int i = 11;
  while (i > 0 && gid < tbl.d[i].woff) --i;
  const SwzDesc m = tbl.d[i];
  long local = gid - m.woff;
  int j = (int)(local & 7);
  int lane = (int)((local >> 3) & 63);
  long rem = local >> 9;
  int KK = m.Kp >> 5;
  int kk = (int)(rem % KK);
  int nt = (int)(rem / KK);
  int k = kk * 32 + (lane >> 4) * 8 + j;
  int n = nt * 16 + (lane & 15);
  float v = (k < m.K) ? m.src[(long)k * m.N + n] : 0.f;
  if (m.mode == 0) {
    unsigned short hi = f2b(v);
    dst[m.dhi + local] = hi;
    dst[m.dlo + local] = f2b(v - b2f(hi));
  } else if (m.mode == 3) {
    _Float16 hi = (_Float16)v;
    dst[m.dhi + local] = __builtin_bit_cast(unsigned short, hi);
    dst[m.dlo + local] = f2h((v - (float)hi) * 2048.f);
  } else {
    dst[m.dhi + local] = f2h(v);
  }
}

// ---------------- encoder (bf16 hi/lo 3-term, one-shot) ----------------------
__global__ __launch_bounds__(512, 2)
void enc_kernel(const float* __restrict__ upast, const float* __restrict__ ypast,
                const unsigned short* __restrict__ W1h, const unsigned short* __restrict__ W1l,
                const unsigned short* __restrict__ W2h, const unsigned short* __restrict__ W2l,
                const unsigned short* __restrict__ W3h, const unsigned short* __restrict__ W3l,
                const unsigned short* __restrict__ rWh, const unsigned short* __restrict__ rWl,
                const float* __restrict__ b1, const float* __restrict__ b2,
                const float* __restrict__ b3, const float* __restrict__ rb,
                float* __restrict__ xstate) {
  __shared__ __align__(16) unsigned short h1h[16][264], h1l[16][264];
  __shared__ __align__(16) unsigned short h2h[16][264], h2l[16][264];
  const int tid = threadIdx.x;
  const int w = tid >> 6, l = tid & 63;
  const int c = l & 15, g = l >> 4;
  const int b0 = blockIdx.x << 4;
  const long zrow = (long)(b0 + c) * 512;

  f4v a0 = zero4(), a1 = zero4();
  for (int kk = 0; kk < 32; ++kk) {
    const int cb = kk * 32 + g * 8;
    const float* zp = (cb < 512) ? (upast + zrow + cb) : (ypast + zrow + (cb - 512));
    float4 z0 = *(const float4*)zp;
    float4 z1 = *(const float4*)(zp + 4);
    float zz[8] = {z0.x, z0.y, z0.z, z0.w, z1.x, z1.y, z1.z, z1.w};
    s8v ah, al;
#pragma unroll
    for (int q = 0; q < 8; ++q) {
      unsigned short hi = f2b(zz[q]);
      ah[q] = (short)hi; al[q] = (short)f2b(zz[q] - b2f(hi));
    }
#pragma unroll
    for (int ct = 0; ct < 2; ++ct) {
      s8v bh = *(const s8v*)(W1h + (((long)(2 * w + ct) * 32 + kk) * 64 + l) * 8);
      s8v bl = *(const s8v*)(W1l + (((long)(2 * w + ct) * 32 + kk) * 64 + l) * 8);
      f4v& acc = ct ? a1 : a0;
      acc = mfma16(ah, bh, acc);
      acc = mfma16(al, bh, acc);
      acc = mfma16(ah, bl, acc);
    }
  }
  {
    const float bbA = b1[(2 * w + 0) * 16 + c], bbB = b1[(2 * w + 1) * 16 + c];
#pragma unroll
    for (int j = 0; j < 4; ++j) {
      float tA = tanhf_fast(a0[j] + bbA), tB = tanhf_fast(a1[j] + bbB);
      unsigned short hA = f2b(tA), hB = f2b(tB);
      h1h[g * 4 + j][(2 * w + 0) * 16 + c] = hA;
      h1l[g * 4 + j][(2 * w + 0) * 16 + c] = f2b(tA - b2f(hA));
      h1h[g * 4 + j][(2 * w + 1) * 16 + c] = hB;
      h1l[g * 4 + j][(2 * w + 1) * 16 + c] = f2b(tB - b2f(hB));
    }
  }
  __syncthreads();
  a0 = zero4(); a1 = zero4();
#pragma unroll
  for (int kk = 0; kk < 8; ++kk) {
    s8v ah = *(const s8v*)(&h1h[c][kk * 32 + g * 8]);
    s8v al = *(const s8v*)(&h1l[c][kk * 32 + g * 8]);
#pragma unroll
    for (int ct = 0; ct < 2; ++ct) {
      s8v bh = *(const s8v*)(W2h + (((long)(2 * w + ct) * 8 + kk) * 64 + l) * 8);
      s8v bl = *(const s8v*)(W2l + (((long)(2 * w + ct) * 8 + kk) * 64 + l) * 8);
      f4v& acc = ct ? a1 : a0;
      acc = mfma16(ah, bh, acc);
      acc = mfma16(al, bh, acc);
      acc = mfma16(ah, bl, acc);
    }
  }
  {
    const float bbA = b2[(2 * w + 0) * 16 + c], bbB = b2[(2 * w + 1) * 16 + c];
#pragma unroll
    for (int j = 0; j < 4; ++j) {
      float tA = tanhf_fast(a0[j] + bbA), tB = tanhf_fast(a1[j] + bbB);
      unsigned short hA = f2b(tA), hB = f2b(tB);
      h2h[g * 4 + j][(2 * w + 0) * 16 + c] = hA;
      h2l[g * 4 + j][(2 * w + 0) * 16 + c] = f2b(tA - b2f(hA));
      h2h[g * 4 + j][(2 * w + 1) * 16 + c] = hB;
      h2l[g * 4 + j][(2 * w + 1) * 16 + c] = f2b(tB - b2f(hB));
    }
  }
  __syncthreads();
  f4v ac = zero4();
#pragma unroll
  for (int kk = 0; kk < 8; ++kk) {
    s8v ah = *(const s8v*)(&h2h[c][kk * 32 + g * 8]);
    s8v al = *(const s8v*)(&h2l[c][kk * 32 + g * 8]);
    s8v bh = *(const s8v*)(W3h + (((long)w * 8 + kk) * 64 + l) * 8);
    s8v bl = *(const s8v*)(W3l + (((long)w * 8 + kk) * 64 + l) * 8);
    ac = mfma16(ah, bh, ac);
    ac = mfma16(al, bh, ac);
    ac = mfma16(ah, bl, ac);
  }
  for (int kk = 0; kk < 32; ++kk) {
    const int cb = kk * 32 + g * 8;
    const float* zp = (cb < 512) ? (upast + zrow + cb) : (ypast + zrow + (cb - 512));
    float4 z0 = *(const float4*)zp;
    float4 z1 = *(const float4*)(zp + 4);
    float zz[8] = {z0.x, z0.y, z0.z, z0.w, z1.x, z1.y, z1.z, z1.w};
    s8v ah, al;
#pragma unroll
    for (int q = 0; q < 8; ++q) {
      unsigned short hi = f2b(zz[q]);
      ah[q] = (short)hi; al[q] = (short)f2b(zz[q] - b2f(hi));
    }
    s8v bh = *(const s8v*)(rWh + (((long)w * 32 + kk) * 64 + l) * 8);
    s8v bl = *(const s8v*)(rWl + (((long)w * 32 + kk) * 64 + l) * 8);
    ac = mfma16(ah, bh, ac);
    ac = mfma16(al, bh, ac);
    ac = mfma16(ah, bl, ac);
  }
  {
    const float bias = b3[w * 16 + c] + rb[w * 16 + c];
#pragma unroll
    for (int j = 0; j < 4; ++j)
      xstate[(long)(b0 + g * 4 + j) * 128 + w * 16 + c] = ac[j] + bias;
  }
}

// ---------------- recurrence (f16 pairs, weights VGPR-resident) --------------
__global__ __launch_bounds__(512, 1)
void recur_kernel(const float* __restrict__ ufut,
                  const unsigned short* __restrict__ W1h, const unsigned short* __restrict__ W1l,
                  const unsigned short* __restrict__ W2h, const unsigned short* __restrict__ W2l,
                  const unsigned short* __restrict__ W3h, const unsigned short* __restrict__ W3l,
                  const unsigned short* __restrict__ rWh, const unsigned short* __restrict__ rWl,
                  const float* __restrict__ b1, const float* __restrict__ b2,
                  const float* __restrict__ b3, const float* __restrict__ rb,
                  float* __restrict__ xstate,
                  unsigned short* __restrict__ xfh, unsigned short* __restrict__ xfl,
                  int t0, int len) {
  __shared__ __align__(16) unsigned short xu_h[2][16][136], xu_l[2][16][136];  // state dbuf
  __shared__ __align__(16) unsigned short h1h[16][264], h1l[16][264];
  __shared__ __align__(16) unsigned short h2h[16][264], h2l[16][264];
  __shared__ __align__(16) unsigned short w3h_l[32768];                        // W3 hi full
  const int tid = threadIdx.x;
  const int w = tid >> 6, l = tid & 63;
  const int c = l & 15, g = l >> 4;
  const int b0 = blockIdx.x << 4;

  // persistent register fragments (184 VGPR): W1 pair, W2 hi, rW pair
  h8v w1h_r[2][5], w1l_r[2][5], w2h_r[2][8], rwh_r[5], rwl_r[5];
#pragma unroll
  for (int ct = 0; ct < 2; ++ct) {
#pragma unroll
    for (int kk = 0; kk < 5; ++kk) {
      w1h_r[ct][kk] = *(const h8v*)(W1h + (((long)(2 * w + ct) * 5 + kk) * 64 + l) * 8);
      w1l_r[ct][kk] = *(const h8v*)(W1l + (((long)(2 * w + ct) * 5 + kk) * 64 + l) * 8);
    }
#pragma unroll
    for (int kk = 0; kk < 8; ++kk)
      w2h_r[ct][kk] = *(const h8v*)(W2h + (((long)(2 * w + ct) * 8 + kk) * 64 + l) * 8);
  }
#pragma unroll
  for (int kk = 0; kk < 5; ++kk) {
    rwh_r[kk] = *(const h8v*)(rWh + (((long)w * 5 + kk) * 64 + l) * 8);
    rwl_r[kk] = *(const h8v*)(rWl + (((long)w * 5 + kk) * 64 + l) * 8);
  }
  // LDS: W3 hi (linear copy)
  for (int i = tid; i < 4096; i += 512)
    ((h8v*)w3h_l)[i] = ((const h8v*)W3h)[i];

  const float bbA = b1[(2 * w + 0) * 16 + c], bbB = b1[(2 * w + 1) * 16 + c];
  const float cbA = b2[(2 * w + 0) * 16 + c], cbB = b2[(2 * w + 1) * 16 + c];
  const float dB  = b3[w * 16 + c] + rb[w * 16 + c];

  // seed state f16 pair into buf 0
  for (int idx = tid; idx < 2048; idx += 512) {
    int r = idx >> 7, cc = idx & 127;
    float x = xstate[(long)(b0 + r) * 128 + cc];
    _Float16 hi = (_Float16)x;
    xu_h[0][r][cc] = __builtin_bit_cast(unsigned short, hi);
    xu_l[0][r][cc] = f2h((x - (float)hi) * 2048.f);
  }
  __syncthreads();

  for (int tc = 0; tc < len; ++tc) {
    const int t = t0 + tc;
    const int cur = tc & 1;
    // u_t fragment (kk=4 of the K=160 padded input): cols 128..143 = u, rest 0
    h8v ah4 = zeroh8(), al4 = zeroh8();
    if (g < 2) {
      const float* up = ufut + ((long)(b0 + c) * 256 + t) * 16 + g * 8;
      float4 u0 = *(const float4*)up;
      float4 u1 = *(const float4*)(up + 4);
      float uu[8] = {u0.x, u0.y, u0.z, u0.w, u1.x, u1.y, u1.z, u1.w};
#pragma unroll
      for (int q = 0; q < 8; ++q) {
        _Float16 hi = (_Float16)uu[q];
        ah4[q] = hi;
        al4[q] = (_Float16)((uu[q] - (float)hi) * 2048.f);
      }
    }
    // xf store (pair) — reads current state buffer (concurrent with G1 reads)
    {
      int r = tid >> 5, cc0 = (tid & 31) * 4;
      long row = ((long)(b0 + r) * len + tc) * 128 + cc0;
      unsigned long long ph =
            (unsigned long long)xu_h[cur][r][cc0 + 0]
          | ((unsigned long long)xu_h[cur][r][cc0 + 1] << 16)
          | ((unsigned long long)xu_h[cur][r][cc0 + 2] << 32)
          | ((unsigned long long)xu_h[cur][r][cc0 + 3] << 48);
      unsigned long long pl =
            (unsigned long long)xu_l[cur][r][cc0 + 0]
          | ((unsigned long long)xu_l[cur][r][cc0 + 1] << 16)
          | ((unsigned long long)xu_l[cur][r][cc0 + 2] << 32)
          | ((unsigned long long)xu_l[cur][r][cc0 + 3] << 48);
      *(unsigned long long*)(xfh + row) = ph;
      *(unsigned long long*)(xfl + row) = pl;
    }
    // GEMM1: xu pair x W1 pair -> h1 pair (A-frags read once per kk)
    {
      f4v p0 = zero4(), q0 = zero4(), p1 = zero4(), q1 = zero4();
#pragma unroll
      for (int kk = 0; kk < 5; ++kk) {
        h8v ah, al;
        if (kk < 4) {
          ah = *(const h8v*)(&xu_h[cur][c][kk * 32 + g * 8]);
          al = *(const h8v*)(&xu_l[cur][c][kk * 32 + g * 8]);
        } else { ah = ah4; al = al4; }
        p0 = mfmaH(ah, w1h_r[0][kk], p0);
        q0 = mfmaH(al, w1h_r[0][kk], q0);
        q0 = mfmaH(ah, w1l_r[0][kk], q0);
        p1 = mfmaH(ah, w1h_r[1][kk], p1);
        q1 = mfmaH(al, w1h_r[1][kk], q1);
        q1 = mfmaH(ah, w1l_r[1][kk], q1);
      }
#pragma unroll
      for (int j = 0; j < 4; ++j) {
        float tA = tanhf_fast(p0[j] + q0[j] * 0x1p-11f + bbA);
        float tB = tanhf_fast(p1[j] + q1[j] * 0x1p-11f + bbB);
        _Float16 hA = (_Float16)tA, hB = (_Float16)tB;
        h1h[g * 4 + j][(2 * w + 0) * 16 + c] = __builtin_bit_cast(unsigned short, hA);
        h1l[g * 4 + j][(2 * w + 0) * 16 + c] = f2h((tA - (float)hA) * 2048.f);
        h1h[g * 4 + j][(2 * w + 1) * 16 + c] = __builtin_bit_cast(unsigned short, hB);
        h1l[g * 4 + j][(2 * w + 1) * 16 + c] = f2h((tB - (float)hB) * 2048.f);
      }
    }
    __syncthreads();  // B1: h1 complete
    // GEMM2: h1 pair x W2 (hi regs, lo from L2) -> h2 pair
    {
      f4v p0 = zero4(), q0 = zero4(), r0 = zero4();
      f4v p1 = zero4(), q1 = zero4(), r1 = zero4();
#pragma unroll
      for (int kk = 0; kk < 8; ++kk) {
        h8v ah = *(const h8v*)(&h1h[c][kk * 32 + g * 8]);
        h8v al = *(const h8v*)(&h1l[c][kk * 32 + g * 8]);
        h8v bl0 = *(const h8v*)(W2l + (((long)(2 * w + 0) * 8 + kk) * 64 + l) * 8);
        h8v bl1 = *(const h8v*)(W2l + (((long)(2 * w + 1) * 8 + kk) * 64 + l) * 8);
        p0 = mfmaH(ah, w2h_r[0][kk], p0);
        q0 = mfmaH(al, w2h_r[0][kk], q0);
        r0 = mfmaH(ah, bl0, r0);
        p1 = mfmaH(ah, w2h_r[1][kk], p1);
        q1 = mfmaH(al, w2h_r[1][kk], q1);
        r1 = mfmaH(ah, bl1, r1);
      }
#pragma unroll
      for (int j = 0; j < 4; ++j) {
        float tA = tanhf_fast(p0[j] + (q0[j] + r0[j]) * 0x1p-11f + cbA);
        float tB = tanhf_fast(p1[j] + (q1[j] + r1[j]) * 0x1p-11f + cbB);
        _Float16 hA = (_Float16)tA, hB = (_Float16)tB;
        h2h[g * 4 + j][(2 * w + 0) * 16 + c] = __builtin_bit_cast(unsigned short, hA);
        h2l[g * 4 + j][(2 * w + 0) * 16 + c] = f2h((tA - (float)hA) * 2048.f);
        h2h[g * 4 + j][(2 * w + 1) * 16 + c] = __builtin_bit_cast(unsigned short, hB);
        h2l[g * 4 + j][(2 * w + 1) * 16 + c] = f2h((tB - (float)hB) * 2048.f);
      }
    }
    __syncthreads();  // B2: h2 complete
    // GEMM3: h2 pair x W3 (hi LDS, lo L2) + xu pair x rW pair (regs)
    {
      f4v p = zero4(), q = zero4(), r = zero4();
#pragma unroll
      for (int kk = 0; kk < 8; ++kk) {
        h8v ah = *(const h8v*)(&h2h[c][kk * 32 + g * 8]);
        h8v al = *(const h8v*)(&h2l[c][kk * 32 + g * 8]);
        h8v bh = *(const h8v*)(&w3h_l[((w * 8 + kk) * 64 + l) * 8]);
        h8v bl = *(const h8v*)(W3l + (((long)w * 8 + kk) * 64 + l) * 8);
        p = mfmaH(ah, bh, p);
        q = mfmaH(al, bh, q);
        r = mfmaH(ah, bl, r);
      }
#pragma unroll
      for (int kk = 0; kk < 5; ++kk) {
        h8v ah, al;
        if (kk < 4) {
          ah = *(const h8v*)(&xu_h[cur][c][kk * 32 + g * 8]);
          al = *(const h8v*)(&xu_l[cur][c][kk * 32 + g * 8]);
        } else { ah = ah4; al = al4; }
        p = mfmaH(ah, rwh_r[kk], p);
        q = mfmaH(al, rwh_r[kk], q);
        r = mfmaH(ah, rwl_r[kk], r);
      }
      // write next state to the OTHER buffer (no pre-write drain needed)
#pragma unroll
      for (int j = 0; j < 4; ++j) {
        float xn = p[j] + (q[j] + r[j]) * 0x1p-11f + dB;
        _Float16 hi = (_Float16)xn;
        xu_h[cur ^ 1][g * 4 + j][w * 16 + c] = __builtin_bit_cast(unsigned short, hi);
        xu_l[cur ^ 1][g * 4 + j][w * 16 + c] = f2h((xn - (float)hi) * 2048.f);
      }
    }
    __syncthreads();  // B3: next state complete
  }
  // chunk-final state writeback (fp32 = hi + lo*2^-11, exact)
  {
    const int fin = len & 1;
    for (int idx = tid; idx < 2048; idx += 512) {
      int r = idx >> 7, cc = idx & 127;
      xstate[(long)(b0 + r) * 128 + cc] =
          h2f(xu_h[fin][r][cc]) + h2f(xu_l[fin][r][cc]) * 0x1p-11f;
    }
  }
}

// ---------------- output network h (xf pair x f16-single weights) ------------
__global__ __launch_bounds__(512, 2)
void hnet_kernel(const unsigned short* __restrict__ xfh, const unsigned short* __restrict__ xfl,
                 const unsigned short* __restrict__ W1, const unsigned short* __restrict__ W2,
                 const unsigned short* __restrict__ W3, const unsigned short* __restrict__ rW,
                 const float* __restrict__ b1, const float* __restrict__ b2,
                 const float* __restrict__ b3, const float* __restrict__ rb,
                 float* __restrict__ out, int t0, int len) {
  __shared__ __align__(16) unsigned short h1[64][264];
  __shared__ __align__(16) unsigned short h2[64][264];
  __shared__ float part[4][16][16];
  const int tid = threadIdx.x;
  const int w = tid >> 6, l = tid & 63;
  const int c = l & 15, g = l >> 4;
  const long row0 = (long)blockIdx.x * 64;

  {  // stage A: h1 = tanh(xf(pair) @ W1 + b1)
    h8v w1f[2][4];
#pragma unroll
    for (int ct = 0; ct < 2; ++ct)
#pragma unroll
      for (int kk = 0; kk < 4; ++kk)
        w1f[ct][kk] = *(const h8v*)(W1 + (((long)(2 * w + ct) * 4 + kk) * 64 + l) * 8);
    const float bbA = b1[(2 * w + 0) * 16 + c], bbB = b1[(2 * w + 1) * 16 + c];
    for (int rt = 0; rt < 4; ++rt) {
      f4v t10 = zero4(), tl0 = zero4(), t11 = zero4(), tl1 = zero4();
#pragma unroll
      for (int kk = 0; kk < 4; ++kk) {
        h8v ah = *(const h8v*)(xfh + (row0 + rt * 16 + c) * 128 + kk * 32 + g * 8);
        h8v al = *(const h8v*)(xfl + (row0 + rt * 16 + c) * 128 + kk * 32 + g * 8);
        t10 = mfmaH(ah, w1f[0][kk], t10);
        tl0 = mfmaH(al, w1f[0][kk], tl0);
        t11 = mfmaH(ah, w1f[1][kk], t11);
        tl1 = mfmaH(al, w1f[1][kk], tl1);
      }
#pragma unroll
      for (int j = 0; j < 4; ++j) {
        h1[rt * 16 + g * 4 + j][(2 * w + 0) * 16 + c] =
            f2h(tanhf_fast(t10[j] + tl0[j] * 0x1p-11f + bbA));
        h1[rt * 16 + g * 4 + j][(2 * w + 1) * 16 + c] =
            f2h(tanhf_fast(t11[j] + tl1[j] * 0x1p-11f + bbB));
      }
    }
  }
  __syncthreads();
  {  // stage B: h2 = tanh(h1 @ W2 + b2), f16 single
    h8v w2f[2][8];
#pragma unroll
    for (int ct = 0; ct < 2; ++ct)
#pragma unroll
      for (int kk = 0; kk < 8; ++kk)
        w2f[ct][kk] = *(const h8v*)(W2 + (((long)(2 * w + ct) * 8 + kk) * 64 + l) * 8);
    const float bbA = b2[(2 * w + 0) * 16 + c], bbB = b2[(2 * w + 1) * 16 + c];
    for (int rt = 0; rt < 4; ++rt) {
      f4v a0 = zero4(), a1 = zero4();
#pragma unroll
      for (int kk = 0; kk < 8; ++kk) {
        h8v a = *(const h8v*)(&h1[rt * 16 + c][kk * 32 + g * 8]);
        a0 = mfmaH(a, w2f[0][kk], a0);
        a1 = mfmaH(a, w2f[1][kk], a1);
      }
#pragma unroll
      for (int j = 0; j < 4; ++j) {
        h2[rt * 16 + g * 4 + j][(2 * w + 0) * 16 + c] = f2h(tanhf_fast(a0[j] + bbA));
        h2[rt * 16 + g * 4 + j][(2 * w + 1) * 16 + c] = f2h(tanhf_fast(a1[j] + bbB));
      }
    }
  }
  __syncthreads();
  {  // stage C: y = h2 @ W3 + xf(pair) @ rW + b3 + rb
    const int rt = w & 3, kh = w >> 2;
    f4v t1 = zero4(), tl = zero4();
#pragma unroll
    for (int kk = 0; kk < 4; ++kk) {
      const int kkg = kh * 4 + kk;
      h8v a = *(const h8v*)(&h2[rt * 16 + c][kkg * 32 + g * 8]);
      h8v b = *(const h8v*)(W3 + ((long)(kkg * 64 + l)) * 8);
      t1 = mfmaH(a, b, t1);
    }
#pragma unroll
    for (int kk = 0; kk < 2; ++kk) {
      const int kkg = kh * 2 + kk;
      h8v ah = *(const h8v*)(xfh + (row0 + rt * 16 + c) * 128 + kkg * 32 + g * 8);
      h8v al = *(const h8v*)(xfl + (row0 + rt * 16 + c) * 128 + kkg * 32 + g * 8);
      h8v b = *(const h8v*)(rW + ((long)(kkg * 64 + l)) * 8);
      t1 = mfmaH(ah, b, t1);
      tl = mfmaH(al, b, tl);
    }
    float val[4];
#pragma unroll
    for (int j = 0; j < 4; ++j) val[j] = t1[j] + tl[j] * 0x1p-11f;
    if (w >= 4) {
#pragma unroll
      for (int j = 0; j < 4; ++j) part[rt][g * 4 + j][c] = val[j];
    }
    __syncthreads();
    if (w < 4) {
      const float bias = b3[c] + rb[c];
#pragma unroll
      for (int j = 0; j < 4; ++j) {
        const long grow = row0 + rt * 16 + g * 4 + j;
        const long bq = grow / len;
        const int tq = (int)(grow - bq * len);
        out[(bq * 256 + (t0 + tq)) * 16 + c] = val[j] + part[rt][g * 4 + j][c] + bias;
      }
    }
  }
}

// ---------------- host -------------------------------------------------------
extern "C" void kernel_launch(void* const* d_in, const int* in_sizes, int n_in,
                              void* d_out, int out_size, void* d_ws, size_t ws_size,
                              hipStream_t stream) {
  (void)in_sizes; (void)n_in; (void)out_size;
  const float* upast = (const float*)d_in[0];
  const float* ypast = (const float*)d_in[1];
  const float* ufut  = (const float*)d_in[2];
  const float* e_rW = (const float*)d_in[3];
  const float* e_rb = (const float*)d_in[4];
  const float* e_W1 = (const float*)d_in[5];
  const float* e_b1 = (const float*)d_in[6];
  const float* e_W2 = (const float*)d_in[7];
  const float* e_b2 = (const float*)d_in[8];
  const float* e_W3 = (const float*)d_in[9];
  const float* e_b3 = (const float*)d_in[10];
  const float* f_rW = (const float*)d_in[11];
  const float* f_rb = (const float*)d_in[12];
  const float* f_W1 = (const float*)d_in[13];
  const float* f_b1 = (const float*)d_in[14];
  const float* f_W2 = (const float*)d_in[15];
  const float* f_b2 = (const float*)d_in[16];
  const float* f_W3 = (const float*)d_in[17];
  const float* f_b3 = (const float*)d_in[18];
  const float* h_rW = (const float*)d_in[19];
  const float* h_rb = (const float*)d_in[20];
  const float* h_W1 = (const float*)d_in[21];
  const float* h_b1 = (const float*)d_in[22];
  const float* h_W2 = (const float*)d_in[23];
  const float* h_b2 = (const float*)d_in[24];
  const float* h_W3 = (const float*)d_in[25];
  const float* h_b3 = (const float*)d_in[26];
  float* out = (float*)d_out;

  // swizzle table: e_* bf16 pair (mode0), f_* f16 pair (mode3), h_* f16 (mode1)
  const float* srcs[12] = { e_W1, e_W2, e_W3, e_rW, f_W1, f_W2, f_W3, f_rW,
                            h_W1, h_W2, h_W3, h_rW };
  const int Ks [12] = {1024, 256, 256, 1024, 144, 256, 256, 144, 128, 256, 256, 128};
  const int Kps[12] = {1024, 256, 256, 1024, 160, 256, 256, 160, 128, 256, 256, 128};
  const int Ns [12] = { 256, 256, 128,  128, 256, 256, 128, 128, 256, 256,  16,  16};
  const int modes[12] = {0,0,0,0, 3,3,3,3, 1,1,1,1};

  SwzTable tbl;
  long woff = 0, offs[12];
  for (int i = 0; i < 12; ++i) { offs[i] = woff; woff += (long)Kps[i] * Ns[i]; }
  const long EA = offs[4];              // e-region elems
  const long FB = 2 * EA;
  const long EB = offs[8] - offs[4];    // f-region elems
  const long HB = FB + 2 * EB;
  for (int i = 0; i < 12; ++i) {
    tbl.d[i].src = srcs[i]; tbl.d[i].woff = offs[i];
    tbl.d[i].K = Ks[i]; tbl.d[i].Kp = Kps[i]; tbl.d[i].N = Ns[i]; tbl.d[i].mode = modes[i];
    if (modes[i] == 0)      { tbl.d[i].dhi = offs[i];              tbl.d[i].dlo = EA + offs[i]; }
    else if (modes[i] == 3) { long lo = offs[i] - offs[4];
                              tbl.d[i].dhi = FB + lo;              tbl.d[i].dlo = FB + EB + lo; }
    else                    { long lo = offs[i] - offs[8];
                              tbl.d[i].dhi = HB + lo;              tbl.d[i].dlo = 0; }
  }
  tbl.tot_work = woff;

  unsigned short* wswz = (unsigned short*)d_ws;
  const long WSHORTS = HB + (offs[11] - offs[8]) + (long)Kps[11] * Ns[11];
  const size_t XOFF = ((size_t)WSHORTS * 2 + 4095) & ~(size_t)4095;
  float* xstate = (float*)((char*)d_ws + XOFF);
  const size_t XF0 = XOFF + (2u << 20);
  int c = 64;
  {
    long cmax = ((long)ws_size - (long)XF0) >> 21;  // 2 MB per time-step (pair)
    if (cmax < c) c = (int)cmax;
    if (c < 1) c = 1;
  }
  unsigned short* xfh = (unsigned short*)((char*)d_ws + XF0);
  unsigned short* xfl = (unsigned short*)((char*)d_ws + XF0 + (size_t)c * 1048576);

  // kernel weight pointers
  const unsigned short* eW1h = wswz + offs[0];          const unsigned short* eW1l = wswz + EA + offs[0];
  const unsigned short* eW2h = wswz + offs[1];          const unsigned short* eW2l = wswz + EA + offs[1];
  const unsigned short* eW3h = wswz + offs[2];          const unsigned short* eW3l = wswz + EA + offs[2];
  const unsigned short* erWh = wswz + offs[3];          const unsigned short* erWl = wswz + EA + offs[3];
  const unsigned short* fW1h = wswz + FB + 0;           const unsigned short* fW1l = wswz + FB + EB + 0;
  const unsigned short* fW2h = wswz + FB + 40960;       const unsigned short* fW2l = wswz + FB + EB + 40960;
  const unsigned short* fW3h = wswz + FB + 106496;      const unsigned short* fW3l = wswz + FB + EB + 106496;
  const unsigned short* frWh = wswz + FB + 139264;      const unsigned short* frWl = wswz + FB + EB + 139264;
  const unsigned short* hW1 = wswz + HB + 0;
  const unsigned short* hW2 = wswz + HB + 32768;
  const unsigned short* hW3 = wswz + HB + 98304;
  const unsigned short* hrW = wswz + HB + 102400;

  swz_kernel<<<(int)((tbl.tot_work + 255) / 256), 256, 0, stream>>>(tbl, wswz);
  enc_kernel<<<256, 512, 0, stream>>>(upast, ypast,
                                      eW1h, eW1l, eW2h, eW2l, eW3h, eW3l, erWh, erWl,
                                      e_b1, e_b2, e_b3, e_rb, xstate);
  for (int t0 = 0; t0 < 256; t0 += c) {
    int len = 256 - t0; if (len > c) len = c;
    recur_kernel<<<256, 512, 0, stream>>>(ufut, fW1h, fW1l, fW2h, fW2l, fW3h, fW3l,
                                          frWh, frWl, f_b1, f_b2, f_b3, f_rb,
                                          xstate, xfh, xfl, t0, len);
    hnet_kernel<<<64 * len, 512, 0, stream>>>(xfh, xfl, hW1, hW2, hW3, hrW,
                                              h_b1, h_b2, h_b3, h_rb, out, t0, len);
  }
}

// Round 6
// 3884.003 us; speedup vs baseline: 1.0019x; 1.0019x over previous
//
#include <hip/hip_runtime.h>
#include <stdint.h>

// SUBNET_15290083574166: encoder MLP -> 256-step recurrent f MLP -> output h MLP
// B=4096, T=256, NX=128, NU=16, NY=16, NB=NA=32, H=256
//
// Precision (VERIFIED r4/r5, absmax 0.0625 vs thr 0.24): f16 hi/lo pairs
// (2^-22) on all recurrence operands, 2-accum (hi + lo*2^-11); encoder bf16
// pairs; hnet xf-pair x f16-single. DO NOT change the numerics.
//
// r6 change (single variable): recur_kernel uses
//   amdgpu_flat_work_group_size(512,512) + amdgpu_waves_per_eu(2,2)
// so the register allocator budgets 256 VGPR/wave (512-reg SIMD pool / 2
// waves). r5's launch_bounds(512,1) left the allocator targeting 4 waves/SIMD
// -> 128-reg cap -> 184 weight VGPRs rematerialized as per-step global
// reloads -> FETCH_SIZE 1.74 GB/dispatch, HBM-bound (830us). LDS (114KB)
// limits to 1 wg/CU = 2 waves/SIMD anyway, so waves_per_eu(2,2) loses nothing.

typedef __attribute__((ext_vector_type(8))) short s8v;      // 8 bf16 bits
typedef __attribute__((ext_vector_type(8))) _Float16 h8v;   // 8 f16
typedef __attribute__((ext_vector_type(4))) float f4v;

__device__ __forceinline__ f4v mfma16(s8v a, s8v b, f4v c) {
  return __builtin_amdgcn_mfma_f32_16x16x32_bf16(a, b, c, 0, 0, 0);
}
__device__ __forceinline__ f4v mfmaH(h8v a, h8v b, f4v c) {
  return __builtin_amdgcn_mfma_f32_16x16x32_f16(a, b, c, 0, 0, 0);
}
__device__ __forceinline__ f4v zero4() { return (f4v){0.f, 0.f, 0.f, 0.f}; }
__device__ __forceinline__ h8v zeroh8() {
  h8v z;
#pragma unroll
  for (int q = 0; q < 8; ++q) z[q] = (_Float16)0.f;
  return z;
}

__device__ __forceinline__ unsigned short f2b(float x) {  // f32->bf16 RNE
  unsigned int u = __builtin_bit_cast(unsigned int, x);
  u += 0x7fffu + ((u >> 16) & 1u);
  return (unsigned short)(u >> 16);
}
__device__ __forceinline__ float b2f(unsigned short h) {
  return __builtin_bit_cast(float, (unsigned int)h << 16);
}
__device__ __forceinline__ unsigned short f2h(float x) {
  return __builtin_bit_cast(unsigned short, (_Float16)x);
}
__device__ __forceinline__ float h2f(unsigned short h) {
  return (float)__builtin_bit_cast(_Float16, h);
}

__device__ __forceinline__ float tanhf_fast(float x) {
  x = fminf(15.f, fmaxf(-15.f, x));
  float e = __expf(2.f * x);
  return (e - 1.f) / (e + 1.f);
}

// ---------------- weight swizzle: fp32 [K][N] -> fragment order ---------------
// frag: idx(nt,kk,lane,j) = ((nt*KK + kk)*64 + lane)*8 + j
//   holds W[kk*32 + (lane>>4)*8 + j][nt*16 + (lane&15)]  (zero-pad k>=K)
// mode 0: bf16 hi at dst[dhi+local], bf16 lo at dst[dlo+local]
// mode 3: f16 hi at dst[dhi+local], f16((v-hi)*2048) at dst[dlo+local]
// mode 1: f16 at dst[dhi+local]
struct SwzDesc { const float* src; long woff; long dhi; long dlo; int K; int Kp; int N; int mode; };
struct SwzTable { SwzDesc d[12]; long tot_work; };

__global__ void swz_kernel(SwzTable tbl, unsigned short* __restrict__ dst) {
  long gid = (long)blockIdx.x * 256 + threadIdx.x;
  if (gid >= tbl.tot_work) return;
  int i = 11;
  while (i > 0 && gid < tbl.d[i].woff) --i;
  const SwzDesc m = tbl.d[i];
  long local = gid - m.woff;
  int j = (int)(local & 7);
  int lane = (int)((local >> 3) & 63);
  long rem = local >> 9;
  int KK = m.Kp >> 5;
  int kk = (int)(rem % KK);
  int nt = (int)(rem / KK);
  int k = kk * 32 + (lane >> 4) * 8 + j;
  int n = nt * 16 + (lane & 15);
  float v = (k < m.K) ? m.src[(long)k * m.N + n] : 0.f;
  if (m.mode == 0) {
    unsigned short hi = f2b(v);
    dst[m.dhi + local] = hi;
    dst[m.dlo + local] = f2b(v - b2f(hi));
  } else if (m.mode == 3) {
    _Float16 hi = (_Float16)v;
    dst[m.dhi + local] = __builtin_bit_cast(unsigned short, hi);
    dst[m.dlo + local] = f2h((v - (float)hi) * 2048.f);
  } else {
    dst[m.dhi + local] = f2h(v);
  }
}

// ---------------- encoder (bf16 hi/lo 3-term, one-shot) ----------------------
__global__ __launch_bounds__(512, 2)
void enc_kernel(const float* __restrict__ upast, const float* __restrict__ ypast,
                const unsigned short* __restrict__ W1h, const unsigned short* __restrict__ W1l,
                const unsigned short* __restrict__ W2h, const unsigned short* __restrict__ W2l,
                const unsigned short* __restrict__ W3h, const unsigned short* __restrict__ W3l,
                const unsigned short* __restrict__ rWh, const unsigned short* __restrict__ rWl,
                const float* __restrict__ b1, const float* __restrict__ b2,
                const float* __restrict__ b3, const float* __restrict__ rb,
                float* __restrict__ xstate) {
  __shared__ __align__(16) unsigned short h1h[16][264], h1l[16][264];
  __shared__ __align__(16) unsigned short h2h[16][264], h2l[16][264];
  const int tid = threadIdx.x;
  const int w = tid >> 6, l = tid & 63;
  const int c = l & 15, g = l >> 4;
  const int b0 = blockIdx.x << 4;
  const long zrow = (long)(b0 + c) * 512;

  f4v a0 = zero4(), a1 = zero4();
  for (int kk = 0; kk < 32; ++kk) {
    const int cb = kk * 32 + g * 8;
    const float* zp = (cb < 512) ? (upast + zrow + cb) : (ypast + zrow + (cb - 512));
    float4 z0 = *(const float4*)zp;
    float4 z1 = *(const float4*)(zp + 4);
    float zz[8] = {z0.x, z0.y, z0.z, z0.w, z1.x, z1.y, z1.z, z1.w};
    s8v ah, al;
#pragma unroll
    for (int q = 0; q < 8; ++q) {
      unsigned short hi = f2b(zz[q]);
      ah[q] = (short)hi; al[q] = (short)f2b(zz[q] - b2f(hi));
    }
#pragma unroll
    for (int ct = 0; ct < 2; ++ct) {
      s8v bh = *(const s8v*)(W1h + (((long)(2 * w + ct) * 32 + kk) * 64 + l) * 8);
      s8v bl = *(const s8v*)(W1l + (((long)(2 * w + ct) * 32 + kk) * 64 + l) * 8);
      f4v& acc = ct ? a1 : a0;
      acc = mfma16(ah, bh, acc);
      acc = mfma16(al, bh, acc);
      acc = mfma16(ah, bl, acc);
    }
  }
  {
    const float bbA = b1[(2 * w + 0) * 16 + c], bbB = b1[(2 * w + 1) * 16 + c];
#pragma unroll
    for (int j = 0; j < 4; ++j) {
      float tA = tanhf_fast(a0[j] + bbA), tB = tanhf_fast(a1[j] + bbB);
      unsigned short hA = f2b(tA), hB = f2b(tB);
      h1h[g * 4 + j][(2 * w + 0) * 16 + c] = hA;
      h1l[g * 4 + j][(2 * w + 0) * 16 + c] = f2b(tA - b2f(hA));
      h1h[g * 4 + j][(2 * w + 1) * 16 + c] = hB;
      h1l[g * 4 + j][(2 * w + 1) * 16 + c] = f2b(tB - b2f(hB));
    }
  }
  __syncthreads();
  a0 = zero4(); a1 = zero4();
#pragma unroll
  for (int kk = 0; kk < 8; ++kk) {
    s8v ah = *(const s8v*)(&h1h[c][kk * 32 + g * 8]);
    s8v al = *(const s8v*)(&h1l[c][kk * 32 + g * 8]);
#pragma unroll
    for (int ct = 0; ct < 2; ++ct) {
      s8v bh = *(const s8v*)(W2h + (((long)(2 * w + ct) * 8 + kk) * 64 + l) * 8);
      s8v bl = *(const s8v*)(W2l + (((long)(2 * w + ct) * 8 + kk) * 64 + l) * 8);
      f4v& acc = ct ? a1 : a0;
      acc = mfma16(ah, bh, acc);
      acc = mfma16(al, bh, acc);
      acc = mfma16(ah, bl, acc);
    }
  }
  {
    const float bbA = b2[(2 * w + 0) * 16 + c], bbB = b2[(2 * w + 1) * 16 + c];
#pragma unroll
    for (int j = 0; j < 4; ++j) {
      float tA = tanhf_fast(a0[j] + bbA), tB = tanhf_fast(a1[j] + bbB);
      unsigned short hA = f2b(tA), hB = f2b(tB);
      h2h[g * 4 + j][(2 * w + 0) * 16 + c] = hA;
      h2l[g * 4 + j][(2 * w + 0) * 16 + c] = f2b(tA - b2f(hA));
      h2h[g * 4 + j][(2 * w + 1) * 16 + c] = hB;
      h2l[g * 4 + j][(2 * w + 1) * 16 + c] = f2b(tB - b2f(hB));
    }
  }
  __syncthreads();
  f4v ac = zero4();
#pragma unroll
  for (int kk = 0; kk < 8; ++kk) {
    s8v ah = *(const s8v*)(&h2h[c][kk * 32 + g * 8]);
    s8v al = *(const s8v*)(&h2l[c][kk * 32 + g * 8]);
    s8v bh = *(const s8v*)(W3h + (((long)w * 8 + kk) * 64 + l) * 8);
    s8v bl = *(const s8v*)(W3l + (((long)w * 8 + kk) * 64 + l) * 8);
    ac = mfma16(ah, bh, ac);
    ac = mfma16(al, bh, ac);
    ac = mfma16(ah, bl, ac);
  }
  for (int kk = 0; kk < 32; ++kk) {
    const int cb = kk * 32 + g * 8;
    const float* zp = (cb < 512) ? (upast + zrow + cb) : (ypast + zrow + (cb - 512));
    float4 z0 = *(const float4*)zp;
    float4 z1 = *(const float4*)(zp + 4);
    float zz[8] = {z0.x, z0.y, z0.z, z0.w, z1.x, z1.y, z1.z, z1.w};
    s8v ah, al;
#pragma unroll
    for (int q = 0; q < 8; ++q) {
      unsigned short hi = f2b(zz[q]);
      ah[q] = (short)hi; al[q] = (short)f2b(zz[q] - b2f(hi));
    }
    s8v bh = *(const s8v*)(rWh + (((long)w * 32 + kk) * 64 + l) * 8);
    s8v bl = *(const s8v*)(rWl + (((long)w * 32 + kk) * 64 + l) * 8);
    ac = mfma16(ah, bh, ac);
    ac = mfma16(al, bh, ac);
    ac = mfma16(ah, bl, ac);
  }
  {
    const float bias = b3[w * 16 + c] + rb[w * 16 + c];
#pragma unroll
    for (int j = 0; j < 4; ++j)
      xstate[(long)(b0 + g * 4 + j) * 128 + w * 16 + c] = ac[j] + bias;
  }
}

// ---------------- recurrence (f16 pairs, weights VGPR-resident) --------------
__global__ __attribute__((amdgpu_flat_work_group_size(512, 512)))
__attribute__((amdgpu_waves_per_eu(2, 2)))
void recur_kernel(const float* __restrict__ ufut,
                  const unsigned short* __restrict__ W1h, const unsigned short* __restrict__ W1l,
                  const unsigned short* __restrict__ W2h, const unsigned short* __restrict__ W2l,
                  const unsigned short* __restrict__ W3h, const unsigned short* __restrict__ W3l,
                  const unsigned short* __restrict__ rWh, const unsigned short* __restrict__ rWl,
                  const float* __restrict__ b1, const float* __restrict__ b2,
                  const float* __restrict__ b3, const float* __restrict__ rb,
                  float* __restrict__ xstate,
                  unsigned short* __restrict__ xfh, unsigned short* __restrict__ xfl,
                  int t0, int len) {
  __shared__ __align__(16) unsigned short xu_h[2][16][136], xu_l[2][16][136];  // state dbuf
  __shared__ __align__(16) unsigned short h1h[16][264], h1l[16][264];
  __shared__ __align__(16) unsigned short h2h[16][264], h2l[16][264];
  __shared__ __align__(16) unsigned short w3h_l[32768];                        // W3 hi full
  const int tid = threadIdx.x;
  const int w = tid >> 6, l = tid & 63;
  const int c = l & 15, g = l >> 4;
  const int b0 = blockIdx.x << 4;

  // persistent register fragments (184 VGPR): W1 pair, W2 hi, rW pair
  h8v w1h_r[2][5], w1l_r[2][5], w2h_r[2][8], rwh_r[5], rwl_r[5];
#pragma unroll
  for (int ct = 0; ct < 2; ++ct) {
#pragma unroll
    for (int kk = 0; kk < 5; ++kk) {
      w1h_r[ct][kk] = *(const h8v*)(W1h + (((long)(2 * w + ct) * 5 + kk) * 64 + l) * 8);
      w1l_r[ct][kk] = *(const h8v*)(W1l + (((long)(2 * w + ct) * 5 + kk) * 64 + l) * 8);
    }
#pragma unroll
    for (int kk = 0; kk < 8; ++kk)
      w2h_r[ct][kk] = *(const h8v*)(W2h + (((long)(2 * w + ct) * 8 + kk) * 64 + l) * 8);
  }
#pragma unroll
  for (int kk = 0; kk < 5; ++kk) {
    rwh_r[kk] = *(const h8v*)(rWh + (((long)w * 5 + kk) * 64 + l) * 8);
    rwl_r[kk] = *(const h8v*)(rWl + (((long)w * 5 + kk) * 64 + l) * 8);
  }
  // LDS: W3 hi (linear copy)
  for (int i = tid; i < 4096; i += 512)
    ((h8v*)w3h_l)[i] = ((const h8v*)W3h)[i];

  const float bbA = b1[(2 * w + 0) * 16 + c], bbB = b1[(2 * w + 1) * 16 + c];
  const float cbA = b2[(2 * w + 0) * 16 + c], cbB = b2[(2 * w + 1) * 16 + c];
  const float dB  = b3[w * 16 + c] + rb[w * 16 + c];

  // seed state f16 pair into buf 0
  for (int idx = tid; idx < 2048; idx += 512) {
    int r = idx >> 7, cc = idx & 127;
    float x = xstate[(long)(b0 + r) * 128 + cc];
    _Float16 hi = (_Float16)x;
    xu_h[0][r][cc] = __builtin_bit_cast(unsigned short, hi);
    xu_l[0][r][cc] = f2h((x - (float)hi) * 2048.f);
  }
  __syncthreads();

  for (int tc = 0; tc < len; ++tc) {
    const int t = t0 + tc;
    const int cur = tc & 1;
    // u_t fragment (kk=4 of the K=160 padded input): cols 128..143 = u, rest 0
    h8v ah4 = zeroh8(), al4 = zeroh8();
    if (g < 2) {
      const float* up = ufut + ((long)(b0 + c) * 256 + t) * 16 + g * 8;
      float4 u0 = *(const float4*)up;
      float4 u1 = *(const float4*)(up + 4);
      float uu[8] = {u0.x, u0.y, u0.z, u0.w, u1.x, u1.y, u1.z, u1.w};
#pragma unroll
      for (int q = 0; q < 8; ++q) {
        _Float16 hi = (_Float16)uu[q];
        ah4[q] = hi;
        al4[q] = (_Float16)((uu[q] - (float)hi) * 2048.f);
      }
    }
    // xf store (pair) — reads current state buffer (concurrent with G1 reads)
    {
      int r = tid >> 5, cc0 = (tid & 31) * 4;
      long row = ((long)(b0 + r) * len + tc) * 128 + cc0;
      unsigned long long ph =
            (unsigned long long)xu_h[cur][r][cc0 + 0]
          | ((unsigned long long)xu_h[cur][r][cc0 + 1] << 16)
          | ((unsigned long long)xu_h[cur][r][cc0 + 2] << 32)
          | ((unsigned long long)xu_h[cur][r][cc0 + 3] << 48);
      unsigned long long pl =
            (unsigned long long)xu_l[cur][r][cc0 + 0]
          | ((unsigned long long)xu_l[cur][r][cc0 + 1] << 16)
          | ((unsigned long long)xu_l[cur][r][cc0 + 2] << 32)
          | ((unsigned long long)xu_l[cur][r][cc0 + 3] << 48);
      *(unsigned long long*)(xfh + row) = ph;
      *(unsigned long long*)(xfl + row) = pl;
    }
    // GEMM1: xu pair x W1 pair -> h1 pair (A-frags read once per kk)
    {
      f4v p0 = zero4(), q0 = zero4(), p1 = zero4(), q1 = zero4();
#pragma unroll
      for (int kk = 0; kk < 5; ++kk) {
        h8v ah, al;
        if (kk < 4) {
          ah = *(const h8v*)(&xu_h[cur][c][kk * 32 + g * 8]);
          al = *(const h8v*)(&xu_l[cur][c][kk * 32 + g * 8]);
        } else { ah = ah4; al = al4; }
        p0 = mfmaH(ah, w1h_r[0][kk], p0);
        q0 = mfmaH(al, w1h_r[0][kk], q0);
        q0 = mfmaH(ah, w1l_r[0][kk], q0);
        p1 = mfmaH(ah, w1h_r[1][kk], p1);
        q1 = mfmaH(al, w1h_r[1][kk], q1);
        q1 = mfmaH(ah, w1l_r[1][kk], q1);
      }
#pragma unroll
      for (int j = 0; j < 4; ++j) {
        float tA = tanhf_fast(p0[j] + q0[j] * 0x1p-11f + bbA);
        float tB = tanhf_fast(p1[j] + q1[j] * 0x1p-11f + bbB);
        _Float16 hA = (_Float16)tA, hB = (_Float16)tB;
        h1h[g * 4 + j][(2 * w + 0) * 16 + c] = __builtin_bit_cast(unsigned short, hA);
        h1l[g * 4 + j][(2 * w + 0) * 16 + c] = f2h((tA - (float)hA) * 2048.f);
        h1h[g * 4 + j][(2 * w + 1) * 16 + c] = __builtin_bit_cast(unsigned short, hB);
        h1l[g * 4 + j][(2 * w + 1) * 16 + c] = f2h((tB - (float)hB) * 2048.f);
      }
    }
    __syncthreads();  // B1: h1 complete
    // GEMM2: h1 pair x W2 (hi regs, lo from L2) -> h2 pair
    {
      f4v p0 = zero4(), q0 = zero4(), r0 = zero4();
      f4v p1 = zero4(), q1 = zero4(), r1 = zero4();
#pragma unroll
      for (int kk = 0; kk < 8; ++kk) {
        h8v ah = *(const h8v*)(&h1h[c][kk * 32 + g * 8]);
        h8v al = *(const h8v*)(&h1l[c][kk * 32 + g * 8]);
        h8v bl0 = *(const h8v*)(W2l + (((long)(2 * w + 0) * 8 + kk) * 64 + l) * 8);
        h8v bl1 = *(const h8v*)(W2l + (((long)(2 * w + 1) * 8 + kk) * 64 + l) * 8);
        p0 = mfmaH(ah, w2h_r[0][kk], p0);
        q0 = mfmaH(al, w2h_r[0][kk], q0);
        r0 = mfmaH(ah, bl0, r0);
        p1 = mfmaH(ah, w2h_r[1][kk], p1);
        q1 = mfmaH(al, w2h_r[1][kk], q1);
        r1 = mfmaH(ah, bl1, r1);
      }
#pragma unroll
      for (int j = 0; j < 4; ++j) {
        float tA = tanhf_fast(p0[j] + (q0[j] + r0[j]) * 0x1p-11f + cbA);
        float tB = tanhf_fast(p1[j] + (q1[j] + r1[j]) * 0x1p-11f + cbB);
        _Float16 hA = (_Float16)tA, hB = (_Float16)tB;
        h2h[g * 4 + j][(2 * w + 0) * 16 + c] = __builtin_bit_cast(unsigned short, hA);
        h2l[g * 4 + j][(2 * w + 0) * 16 + c] = f2h((tA - (float)hA) * 2048.f);
        h2h[g * 4 + j][(2 * w + 1) * 16 + c] = __builtin_bit_cast(unsigned short, hB);
        h2l[g * 4 + j][(2 * w + 1) * 16 + c] = f2h((tB - (float)hB) * 2048.f);
      }
    }
    __syncthreads();  // B2: h2 complete
    // GEMM3: h2 pair x W3 (hi LDS, lo L2) + xu pair x rW pair (regs)
    {
      f4v p = zero4(), q = zero4(), r = zero4();
#pragma unroll
      for (int kk = 0; kk < 8; ++kk) {
        h8v ah = *(const h8v*)(&h2h[c][kk * 32 + g * 8]);
        h8v al = *(const h8v*)(&h2l[c][kk * 32 + g * 8]);
        h8v bh = *(const h8v*)(&w3h_l[((w * 8 + kk) * 64 + l) * 8]);
        h8v bl = *(const h8v*)(W3l + (((long)w * 8 + kk) * 64 + l) * 8);
        p = mfmaH(ah, bh, p);
        q = mfmaH(al, bh, q);
        r = mfmaH(ah, bl, r);
      }
#pragma unroll
      for (int kk = 0; kk < 5; ++kk) {
        h8v ah, al;
        if (kk < 4) {
          ah = *(const h8v*)(&xu_h[cur][c][kk * 32 + g * 8]);
          al = *(const h8v*)(&xu_l[cur][c][kk * 32 + g * 8]);
        } else { ah = ah4; al = al4; }
        p = mfmaH(ah, rwh_r[kk], p);
        q = mfmaH(al, rwh_r[kk], q);
        r = mfmaH(ah, rwl_r[kk], r);
      }
      // write next state to the OTHER buffer (no pre-write drain needed)
#pragma unroll
      for (int j = 0; j < 4; ++j) {
        float xn = p[j] + (q[j] + r[j]) * 0x1p-11f + dB;
        _Float16 hi = (_Float16)xn;
        xu_h[cur ^ 1][g * 4 + j][w * 16 + c] = __builtin_bit_cast(unsigned short, hi);
        xu_l[cur ^ 1][g * 4 + j][w * 16 + c] = f2h((xn - (float)hi) * 2048.f);
      }
    }
    __syncthreads();  // B3: next state complete
  }
  // chunk-final state writeback (fp32 = hi + lo*2^-11, exact)
  {
    const int fin = len & 1;
    for (int idx = tid; idx < 2048; idx += 512) {
      int r = idx >> 7, cc = idx & 127;
      xstate[(long)(b0 + r) * 128 + cc] =
          h2f(xu_h[fin][r][cc]) + h2f(xu_l[fin][r][cc]) * 0x1p-11f;
    }
  }
}

// ---------------- output network h (xf pair x f16-single weights) ------------
__global__ __launch_bounds__(512, 2)
void hnet_kernel(const unsigned short* __restrict__ xfh, const unsigned short* __restrict__ xfl,
                 const unsigned short* __restrict__ W1, const unsigned short* __restrict__ W2,
                 const unsigned short* __restrict__ W3, const unsigned short* __restrict__ rW,
                 const float* __restrict__ b1, const float* __restrict__ b2,
                 const float* __restrict__ b3, const float* __restrict__ rb,
                 float* __restrict__ out, int t0, int len) {
  __shared__ __align__(16) unsigned short h1[64][264];
  __shared__ __align__(16) unsigned short h2[64][264];
  __shared__ float part[4][16][16];
  const int tid = threadIdx.x;
  const int w = tid >> 6, l = tid & 63;
  const int c = l & 15, g = l >> 4;
  const long row0 = (long)blockIdx.x * 64;

  {  // stage A: h1 = tanh(xf(pair) @ W1 + b1)
    h8v w1f[2][4];
#pragma unroll
    for (int ct = 0; ct < 2; ++ct)
#pragma unroll
      for (int kk = 0; kk < 4; ++kk)
        w1f[ct][kk] = *(const h8v*)(W1 + (((long)(2 * w + ct) * 4 + kk) * 64 + l) * 8);
    const float bbA = b1[(2 * w + 0) * 16 + c], bbB = b1[(2 * w + 1) * 16 + c];
    for (int rt = 0; rt < 4; ++rt) {
      f4v t10 = zero4(), tl0 = zero4(), t11 = zero4(), tl1 = zero4();
#pragma unroll
      for (int kk = 0; kk < 4; ++kk) {
        h8v ah = *(const h8v*)(xfh + (row0 + rt * 16 + c) * 128 + kk * 32 + g * 8);
        h8v al = *(const h8v*)(xfl + (row0 + rt * 16 + c) * 128 + kk * 32 + g * 8);
        t10 = mfmaH(ah, w1f[0][kk], t10);
        tl0 = mfmaH(al, w1f[0][kk], tl0);
        t11 = mfmaH(ah, w1f[1][kk], t11);
        tl1 = mfmaH(al, w1f[1][kk], tl1);
      }
#pragma unroll
      for (int j = 0; j < 4; ++j) {
        h1[rt * 16 + g * 4 + j][(2 * w + 0) * 16 + c] =
            f2h(tanhf_fast(t10[j] + tl0[j] * 0x1p-11f + bbA));
        h1[rt * 16 + g * 4 + j][(2 * w + 1) * 16 + c] =
            f2h(tanhf_fast(t11[j] + tl1[j] * 0x1p-11f + bbB));
      }
    }
  }
  __syncthreads();
  {  // stage B: h2 = tanh(h1 @ W2 + b2), f16 single
    h8v w2f[2][8];
#pragma unroll
    for (int ct = 0; ct < 2; ++ct)
#pragma unroll
      for (int kk = 0; kk < 8; ++kk)
        w2f[ct][kk] = *(const h8v*)(W2 + (((long)(2 * w + ct) * 8 + kk) * 64 + l) * 8);
    const float bbA = b2[(2 * w + 0) * 16 + c], bbB = b2[(2 * w + 1) * 16 + c];
    for (int rt = 0; rt < 4; ++rt) {
      f4v a0 = zero4(), a1 = zero4();
#pragma unroll
      for (int kk = 0; kk < 8; ++kk) {
        h8v a = *(const h8v*)(&h1[rt * 16 + c][kk * 32 + g * 8]);
        a0 = mfmaH(a, w2f[0][kk], a0);
        a1 = mfmaH(a, w2f[1][kk], a1);
      }
#pragma unroll
      for (int j = 0; j < 4; ++j) {
        h2[rt * 16 + g * 4 + j][(2 * w + 0) * 16 + c] = f2h(tanhf_fast(a0[j] + bbA));
        h2[rt * 16 + g * 4 + j][(2 * w + 1) * 16 + c] = f2h(tanhf_fast(a1[j] + bbB));
      }
    }
  }
  __syncthreads();
  {  // stage C: y = h2 @ W3 + xf(pair) @ rW + b3 + rb
    const int rt = w & 3, kh = w >> 2;
    f4v t1 = zero4(), tl = zero4();
#pragma unroll
    for (int kk = 0; kk < 4; ++kk) {
      const int kkg = kh * 4 + kk;
      h8v a = *(const h8v*)(&h2[rt * 16 + c][kkg * 32 + g * 8]);
      h8v b = *(const h8v*)(W3 + ((long)(kkg * 64 + l)) * 8);
      t1 = mfmaH(a, b, t1);
    }
#pragma unroll
    for (int kk = 0; kk < 2; ++kk) {
      const int kkg = kh * 2 + kk;
      h8v ah = *(const h8v*)(xfh + (row0 + rt * 16 + c) * 128 + kkg * 32 + g * 8);
      h8v al = *(const h8v*)(xfl + (row0 + rt * 16 + c) * 128 + kkg * 32 + g * 8);
      h8v b = *(const h8v*)(rW + ((long)(kkg * 64 + l)) * 8);
      t1 = mfmaH(ah, b, t1);
      tl = mfmaH(al, b, tl);
    }
    float val[4];
#pragma unroll
    for (int j = 0; j < 4; ++j) val[j] = t1[j] + tl[j] * 0x1p-11f;
    if (w >= 4) {
#pragma unroll
      for (int j = 0; j < 4; ++j) part[rt][g * 4 + j][c] = val[j];
    }
    __syncthreads();
    if (w < 4) {
      const float bias = b3[c] + rb[c];
#pragma unroll
      for (int j = 0; j < 4; ++j) {
        const long grow = row0 + rt * 16 + g * 4 + j;
        const long bq = grow / len;
        const int tq = (int)(grow - bq * len);
        out[(bq * 256 + (t0 + tq)) * 16 + c] = val[j] + part[rt][g * 4 + j][c] + bias;
      }
    }
  }
}

// ---------------- host -------------------------------------------------------
extern "C" void kernel_launch(void* const* d_in, const int* in_sizes, int n_in,
                              void* d_out, int out_size, void* d_ws, size_t ws_size,
                              hipStream_t stream) {
  (void)in_sizes; (void)n_in; (void)out_size;
  const float* upast = (const float*)d_in[0];
  const float* ypast = (const float*)d_in[1];
  const float* ufut  = (const float*)d_in[2];
  const float* e_rW = (const float*)d_in[3];
  const float* e_rb = (const float*)d_in[4];
  const float* e_W1 = (const float*)d_in[5];
  const float* e_b1 = (const float*)d_in[6];
  const float* e_W2 = (const float*)d_in[7];
  const float* e_b2 = (const float*)d_in[8];
  const float* e_W3 = (const float*)d_in[9];
  const float* e_b3 = (const float*)d_in[10];
  const float* f_rW = (const float*)d_in[11];
  const float* f_rb = (const float*)d_in[12];
  const float* f_W1 = (const float*)d_in[13];
  const float* f_b1 = (const float*)d_in[14];
  const float* f_W2 = (const float*)d_in[15];
  const float* f_b2 = (const float*)d_in[16];
  const float* f_W3 = (const float*)d_in[17];
  const float* f_b3 = (const float*)d_in[18];
  const float* h_rW = (const float*)d_in[19];
  const float* h_rb = (const float*)d_in[20];
  const float* h_W1 = (const float*)d_in[21];
  const float* h_b1 = (const float*)d_in[22];
  const float* h_W2 = (const float*)d_in[23];
  const float* h_b2 = (const float*)d_in[24];
  const float* h_W3 = (const float*)d_in[25];
  const float* h_b3 = (const float*)d_in[26];
  float* out = (float*)d_out;

  // swizzle table: e_* bf16 pair (mode0), f_* f16 pair (mode3), h_* f16 (mode1)
  const float* srcs[12] = { e_W1, e_W2, e_W3, e_rW, f_W1, f_W2, f_W3, f_rW,
                            h_W1, h_W2, h_W3, h_rW };
  const int Ks [12] = {1024, 256, 256, 1024, 144, 256, 256, 144, 128, 256, 256, 128};
  const int Kps[12] = {1024, 256, 256, 1024, 160, 256, 256, 160, 128, 256, 256, 128};
  const int Ns [12] = { 256, 256, 128,  128, 256, 256, 128, 128, 256, 256,  16,  16};
  const int modes[12] = {0,0,0,0, 3,3,3,3, 1,1,1,1};

  SwzTable tbl;
  long woff = 0, offs[12];
  for (int i = 0; i < 12; ++i) { offs[i] = woff; woff += (long)Kps[i] * Ns[i]; }
  const long EA = offs[4];              // e-region elems
  const long FB = 2 * EA;
  const long EB = offs[8] - offs[4];    // f-region elems
  const long HB = FB + 2 * EB;
  for (int i = 0; i < 12; ++i) {
    tbl.d[i].src = srcs[i]; tbl.d[i].woff = offs[i];
    tbl.d[i].K = Ks[i]; tbl.d[i].Kp = Kps[i]; tbl.d[i].N = Ns[i]; tbl.d[i].mode = modes[i];
    if (modes[i] == 0)      { tbl.d[i].dhi = offs[i];              tbl.d[i].dlo = EA + offs[i]; }
    else if (modes[i] == 3) { long lo = offs[i] - offs[4];
                              tbl.d[i].dhi = FB + lo;              tbl.d[i].dlo = FB + EB + lo; }
    else                    { long lo = offs[i] - offs[8];
                              tbl.d[i].dhi = HB + lo;              tbl.d[i].dlo = 0; }
  }
  tbl.tot_work = woff;

  unsigned short* wswz = (unsigned short*)d_ws;
  const long WSHORTS = HB + (offs[11] - offs[8]) + (long)Kps[11] * Ns[11];
  const size_t XOFF = ((size_t)WSHORTS * 2 + 4095) & ~(size_t)4095;
  float* xstate = (float*)((char*)d_ws + XOFF);
  const size_t XF0 = XOFF + (2u << 20);
  int c = 64;
  {
    long cmax = ((long)ws_size - (long)XF0) >> 21;  // 2 MB per time-step (pair)
    if (cmax < c) c = (int)cmax;
    if (c < 1) c = 1;
  }
  unsigned short* xfh = (unsigned short*)((char*)d_ws + XF0);
  unsigned short* xfl = (unsigned short*)((char*)d_ws + XF0 + (size_t)c * 1048576);

  // kernel weight pointers
  const unsigned short* eW1h = wswz + offs[0];          const unsigned short* eW1l = wswz + EA + offs[0];
  const unsigned short* eW2h = wswz + offs[1];          const unsigned short* eW2l = wswz + EA + offs[1];
  const unsigned short* eW3h = wswz + offs[2];          const unsigned short* eW3l = wswz + EA + offs[2];
  const unsigned short* erWh = wswz + offs[3];          const unsigned short* erWl = wswz + EA + offs[3];
  const unsigned short* fW1h = wswz + FB + 0;           const unsigned short* fW1l = wswz + FB + EB + 0;
  const unsigned short* fW2h = wswz + FB + 40960;       const unsigned short* fW2l = wswz + FB + EB + 40960;
  const unsigned short* fW3h = wswz + FB + 106496;      const unsigned short* fW3l = wswz + FB + EB + 106496;
  const unsigned short* frWh = wswz + FB + 139264;      const unsigned short* frWl = wswz + FB + EB + 139264;
  const unsigned short* hW1 = wswz + HB + 0;
  const unsigned short* hW2 = wswz + HB + 32768;
  const unsigned short* hW3 = wswz + HB + 98304;
  const unsigned short* hrW = wswz + HB + 102400;

  swz_kernel<<<(int)((tbl.tot_work + 255) / 256), 256, 0, stream>>>(tbl, wswz);
  enc_kernel<<<256, 512, 0, stream>>>(upast, ypast,
                                      eW1h, eW1l, eW2h, eW2l, eW3h, eW3l, erWh, erWl,
                                      e_b1, e_b2, e_b3, e_rb, xstate);
  for (int t0 = 0; t0 < 256; t0 += c) {
    int len = 256 - t0; if (len > c) len = c;
    recur_kernel<<<256, 512, 0, stream>>>(ufut, fW1h, fW1l, fW2h, fW2l, fW3h, fW3l,
                                          frWh, frWl, f_b1, f_b2, f_b3, f_rb,
                                          xstate, xfh, xfl, t0, len);
    hnet_kernel<<<64 * len, 512, 0, stream>>>(xfh, xfl, hW1, hW2, hW3, hrW,
                                              h_b1, h_b2, h_b3, h_rb, out, t0, len);
  }
}

// Round 7
// 3186.351 us; speedup vs baseline: 1.2213x; 1.2190x over previous
//
#include <hip/hip_runtime.h>
#include <stdint.h>

// SUBNET_15290083574166: encoder MLP -> 256-step recurrent f MLP -> output h MLP
// B=4096, T=256, NX=128, NU=16, NY=16, NB=NA=32, H=256
//
// Precision (VERIFIED r4-r6, absmax 0.0625 vs thr 0.24): f16 hi/lo pairs
// (2^-22) on all recurrence operands, 2-accum (hi + lo*2^-11); encoder bf16
// pairs; hnet xf-pair x f16-single. DO NOT change the numerics.
//
// r7 redesign of recur (r5/r6 lesson: reg demand > 128 => compiler demotes
// persistent weights to per-step global reloads, 1.7GB HBM/dispatch):
//  - 1024 thr / 16 waves, ONE coltile per wave -> persistent regs = 52
//    (W1hi 20 + W2hi 32), forced fit via __launch_bounds__(1024,4)
//  - W3hi (64KB) + rWhi (40KB) in LDS; W1lo/W2lo/W3lo/rWlo streamed from L2
//    per step (laundered base pointer blocks LICM -> predictable codegen)
//  - G3 split: waves 0-7 h2@W3, waves 8-15 xu@rW -> f32 partials in LDS
//  - 4 barriers/step (xf store folded into G1, u-staging into phase D)
//  - 4 waves/SIMD occupancy (was 2)

typedef __attribute__((ext_vector_type(8))) short s8v;      // 8 bf16 bits
typedef __attribute__((ext_vector_type(8))) _Float16 h8v;   // 8 f16
typedef __attribute__((ext_vector_type(4))) float f4v;

__device__ __forceinline__ f4v mfma16(s8v a, s8v b, f4v c) {
  return __builtin_amdgcn_mfma_f32_16x16x32_bf16(a, b, c, 0, 0, 0);
}
__device__ __forceinline__ f4v mfmaH(h8v a, h8v b, f4v c) {
  return __builtin_amdgcn_mfma_f32_16x16x32_f16(a, b, c, 0, 0, 0);
}
__device__ __forceinline__ f4v zero4() { return (f4v){0.f, 0.f, 0.f, 0.f}; }

__device__ __forceinline__ unsigned short f2b(float x) {  // f32->bf16 RNE
  unsigned int u = __builtin_bit_cast(unsigned int, x);
  u += 0x7fffu + ((u >> 16) & 1u);
  return (unsigned short)(u >> 16);
}
__device__ __forceinline__ float b2f(unsigned short h) {
  return __builtin_bit_cast(float, (unsigned int)h << 16);
}
__device__ __forceinline__ unsigned short f2h(float x) {
  return __builtin_bit_cast(unsigned short, (_Float16)x);
}
__device__ __forceinline__ float h2f(unsigned short h) {
  return (float)__builtin_bit_cast(_Float16, h);
}

__device__ __forceinline__ float tanhf_fast(float x) {
  x = fminf(15.f, fmaxf(-15.f, x));
  float e = __expf(2.f * x);
  return (e - 1.f) / (e + 1.f);
}

// ---------------- weight swizzle: fp32 [K][N] -> fragment order ---------------
// frag: idx(nt,kk,lane,j) = ((nt*KK + kk)*64 + lane)*8 + j
//   holds W[kk*32 + (lane>>4)*8 + j][nt*16 + (lane&15)]  (zero-pad k>=K)
// mode 0: bf16 hi at dst[dhi+local], bf16 lo at dst[dlo+local]
// mode 3: f16 hi at dst[dhi+local], f16((v-hi)*2048) at dst[dlo+local]
// mode 1: f16 at dst[dhi+local]
struct SwzDesc { const float* src; long woff; long dhi; long dlo; int K; int Kp; int N; int mode; };
struct SwzTable { SwzDesc d[12]; long tot_work; };

__global__ void swz_kernel(SwzTable tbl, unsigned short* __restrict__ dst) {
  long gid = (long)blockIdx.x * 256 + threadIdx.x;
  if (gid >= tbl.tot_work) return;
  int i = 11;
  while (i > 0 && gid < tbl.d[i].woff) --i;
  const SwzDesc m = tbl.d[i];
  long local = gid - m.woff;
  int j = (int)(local & 7);
  int lane = (int)((local >> 3) & 63);
  long rem = local >> 9;
  int KK = m.Kp >> 5;
  int kk = (int)(rem % KK);
  int nt = (int)(rem / KK);
  int k = kk * 32 + (lane >> 4) * 8 + j;
  int n = nt * 16 + (lane & 15);
  float v = (k < m.K) ? m.src[(long)k * m.N + n] : 0.f;
  if (m.mode == 0) {
    unsigned short hi = f2b(v);
    dst[m.dhi + local] = hi;
    dst[m.dlo + local] = f2b(v - b2f(hi));
  } else if (m.mode == 3) {
    _Float16 hi = (_Float16)v;
    dst[m.dhi + local] = __builtin_bit_cast(unsigned short, hi);
    dst[m.dlo + local] = f2h((v - (float)hi) * 2048.f);
  } else {
    dst[m.dhi + local] = f2h(v);
  }
}

// ---------------- encoder (bf16 hi/lo 3-term, one-shot) ----------------------
__global__ __launch_bounds__(512, 2)
void enc_kernel(const float* __restrict__ upast, const float* __restrict__ ypast,
                const unsigned short* __restrict__ W1h, const unsigned short* __restrict__ W1l,
                const unsigned short* __restrict__ W2h, const unsigned short* __restrict__ W2l,
                const unsigned short* __restrict__ W3h, const unsigned short* __restrict__ W3l,
                const unsigned short* __restrict__ rWh, const unsigned short* __restrict__ rWl,
                const float* __restrict__ b1, const float* __restrict__ b2,
                const float* __restrict__ b3, const float* __restrict__ rb,
                float* __restrict__ xstate) {
  __shared__ __align__(16) unsigned short h1h[16][264], h1l[16][264];
  __shared__ __align__(16) unsigned short h2h[16][264], h2l[16][264];
  const int tid = threadIdx.x;
  const int w = tid >> 6, l = tid & 63;
  const int c = l & 15, g = l >> 4;
  const int b0 = blockIdx.x << 4;
  const long zrow = (long)(b0 + c) * 512;

  f4v a0 = zero4(), a1 = zero4();
  for (int kk = 0; kk < 32; ++kk) {
    const int cb = kk * 32 + g * 8;
    const float* zp = (cb < 512) ? (upast + zrow + cb) : (ypast + zrow + (cb - 512));
    float4 z0 = *(const float4*)zp;
    float4 z1 = *(const float4*)(zp + 4);
    float zz[8] = {z0.x, z0.y, z0.z, z0.w, z1.x, z1.y, z1.z, z1.w};
    s8v ah, al;
#pragma unroll
    for (int q = 0; q < 8; ++q) {
      unsigned short hi = f2b(zz[q]);
      ah[q] = (short)hi; al[q] = (short)f2b(zz[q] - b2f(hi));
    }
#pragma unroll
    for (int ct = 0; ct < 2; ++ct) {
      s8v bh = *(const s8v*)(W1h + (((long)(2 * w + ct) * 32 + kk) * 64 + l) * 8);
      s8v bl = *(const s8v*)(W1l + (((long)(2 * w + ct) * 32 + kk) * 64 + l) * 8);
      f4v& acc = ct ? a1 : a0;
      acc = mfma16(ah, bh, acc);
      acc = mfma16(al, bh, acc);
      acc = mfma16(ah, bl, acc);
    }
  }
  {
    const float bbA = b1[(2 * w + 0) * 16 + c], bbB = b1[(2 * w + 1) * 16 + c];
#pragma unroll
    for (int j = 0; j < 4; ++j) {
      float tA = tanhf_fast(a0[j] + bbA), tB = tanhf_fast(a1[j] + bbB);
      unsigned short hA = f2b(tA), hB = f2b(tB);
      h1h[g * 4 + j][(2 * w + 0) * 16 + c] = hA;
      h1l[g * 4 + j][(2 * w + 0) * 16 + c] = f2b(tA - b2f(hA));
      h1h[g * 4 + j][(2 * w + 1) * 16 + c] = hB;
      h1l[g * 4 + j][(2 * w + 1) * 16 + c] = f2b(tB - b2f(hB));
    }
  }
  __syncthreads();
  a0 = zero4(); a1 = zero4();
#pragma unroll
  for (int kk = 0; kk < 8; ++kk) {
    s8v ah = *(const s8v*)(&h1h[c][kk * 32 + g * 8]);
    s8v al = *(const s8v*)(&h1l[c][kk * 32 + g * 8]);
#pragma unroll
    for (int ct = 0; ct < 2; ++ct) {
      s8v bh = *(const s8v*)(W2h + (((long)(2 * w + ct) * 8 + kk) * 64 + l) * 8);
      s8v bl = *(const s8v*)(W2l + (((long)(2 * w + ct) * 8 + kk) * 64 + l) * 8);
      f4v& acc = ct ? a1 : a0;
      acc = mfma16(ah, bh, acc);
      acc = mfma16(al, bh, acc);
      acc = mfma16(ah, bl, acc);
    }
  }
  {
    const float bbA = b2[(2 * w + 0) * 16 + c], bbB = b2[(2 * w + 1) * 16 + c];
#pragma unroll
    for (int j = 0; j < 4; ++j) {
      float tA = tanhf_fast(a0[j] + bbA), tB = tanhf_fast(a1[j] + bbB);
      unsigned short hA = f2b(tA), hB = f2b(tB);
      h2h[g * 4 + j][(2 * w + 0) * 16 + c] = hA;
      h2l[g * 4 + j][(2 * w + 0) * 16 + c] = f2b(tA - b2f(hA));
      h2h[g * 4 + j][(2 * w + 1) * 16 + c] = hB;
      h2l[g * 4 + j][(2 * w + 1) * 16 + c] = f2b(tB - b2f(hB));
    }
  }
  __syncthreads();
  f4v ac = zero4();
#pragma unroll
  for (int kk = 0; kk < 8; ++kk) {
    s8v ah = *(const s8v*)(&h2h[c][kk * 32 + g * 8]);
    s8v al = *(const s8v*)(&h2l[c][kk * 32 + g * 8]);
    s8v bh = *(const s8v*)(W3h + (((long)w * 8 + kk) * 64 + l) * 8);
    s8v bl = *(const s8v*)(W3l + (((long)w * 8 + kk) * 64 + l) * 8);
    ac = mfma16(ah, bh, ac);
    ac = mfma16(al, bh, ac);
    ac = mfma16(ah, bl, ac);
  }
  for (int kk = 0; kk < 32; ++kk) {
    const int cb = kk * 32 + g * 8;
    const float* zp = (cb < 512) ? (upast + zrow + cb) : (ypast + zrow + (cb - 512));
    float4 z0 = *(const float4*)zp;
    float4 z1 = *(const float4*)(zp + 4);
    float zz[8] = {z0.x, z0.y, z0.z, z0.w, z1.x, z1.y, z1.z, z1.w};
    s8v ah, al;
#pragma unroll
    for (int q = 0; q < 8; ++q) {
      unsigned short hi = f2b(zz[q]);
      ah[q] = (short)hi; al[q] = (short)f2b(zz[q] - b2f(hi));
    }
    s8v bh = *(const s8v*)(rWh + (((long)w * 32 + kk) * 64 + l) * 8);
    s8v bl = *(const s8v*)(rWl + (((long)w * 32 + kk) * 64 + l) * 8);
    ac = mfma16(ah, bh, ac);
    ac = mfma16(al, bh, ac);
    ac = mfma16(ah, bl, ac);
  }
  {
    const float bias = b3[w * 16 + c] + rb[w * 16 + c];
#pragma unroll
    for (int j = 0; j < 4; ++j)
      xstate[(long)(b0 + g * 4 + j) * 128 + w * 16 + c] = ac[j] + bias;
  }
}

// ---------------- recurrence (16 waves, 1 coltile/wave) ----------------------
__global__ __launch_bounds__(1024, 4)
void recur_kernel(const float* __restrict__ ufut,
                  const unsigned short* __restrict__ W1h, const unsigned short* __restrict__ W1l,
                  const unsigned short* __restrict__ W2h, const unsigned short* __restrict__ W2l,
                  const unsigned short* __restrict__ W3h, const unsigned short* __restrict__ W3l,
                  const unsigned short* __restrict__ rWh, const unsigned short* __restrict__ rWl,
                  const float* __restrict__ b1, const float* __restrict__ b2,
                  const float* __restrict__ b3, const float* __restrict__ rb,
                  float* __restrict__ xstate,
                  unsigned short* __restrict__ xfh, unsigned short* __restrict__ xfl,
                  int t0, int len) {
  __shared__ __align__(16) unsigned short xu_h[16][168], xu_l[16][168];
  __shared__ __align__(16) unsigned short h1h[16][264], h1l[16][264];
  __shared__ __align__(16) unsigned short h2h[16][264], h2l[16][264];
  __shared__ __align__(16) unsigned short w3h_l[32768];  // W3 hi  (64 KB)
  __shared__ __align__(16) unsigned short rwh_l[20480];  // rW hi  (40 KB)
  __shared__ __align__(16) float part[16][136];          // rW partial (8.5 KB)
  const int tid = threadIdx.x;
  const int w = tid >> 6, l = tid & 63;
  const int c = l & 15, g = l >> 4;
  const int b0 = blockIdx.x << 4;

  // persistent regs: 52 VGPR (W1 hi 20, W2 hi 32)
  h8v w1h_r[5], w2h_r[8];
#pragma unroll
  for (int kk = 0; kk < 5; ++kk)
    w1h_r[kk] = *(const h8v*)(W1h + (((long)w * 5 + kk) * 64 + l) * 8);
#pragma unroll
  for (int kk = 0; kk < 8; ++kk)
    w2h_r[kk] = *(const h8v*)(W2h + (((long)w * 8 + kk) * 64 + l) * 8);

  // LDS weights (linear copies)
  for (int i = tid; i < 4096; i += 1024) ((h8v*)w3h_l)[i] = ((const h8v*)W3h)[i];
  for (int i = tid; i < 2560; i += 1024) ((h8v*)rwh_l)[i] = ((const h8v*)rWh)[i];

  const float bb = b1[w * 16 + c];
  const float cb = b2[w * 16 + c];
  const float dB = (w < 8) ? (b3[w * 16 + c] + rb[w * 16 + c]) : 0.f;

  // seed state pair; zero k-pad cols 144..159; stage u for t0
  for (int idx = tid; idx < 2048; idx += 1024) {
    int r = idx >> 7, cc = idx & 127;
    float x = xstate[(long)(b0 + r) * 128 + cc];
    _Float16 hi = (_Float16)x;
    xu_h[r][cc] = __builtin_bit_cast(unsigned short, hi);
    xu_l[r][cc] = f2h((x - (float)hi) * 2048.f);
  }
  if (tid < 256) {
    int r = tid >> 4, cc = tid & 15;
    xu_h[r][144 + cc] = 0; xu_l[r][144 + cc] = 0;
    float uv = ufut[((long)(b0 + r) * 256 + t0) * 16 + cc];
    _Float16 hi = (_Float16)uv;
    xu_h[r][128 + cc] = __builtin_bit_cast(unsigned short, hi);
    xu_l[r][128 + cc] = f2h((uv - (float)hi) * 2048.f);
  }
  __syncthreads();

  for (int tc = 0; tc < len; ++tc) {
    const int t = t0 + tc;
    // launder streamed-weight bases: blocks LICM hoist -> per-step L2 reads
    long lz = 0;
    asm volatile("" : "+s"(lz));
    const unsigned short* W1ls = W1l + lz;
    const unsigned short* W2ls = W2l + lz;
    const unsigned short* W3ls = W3l + lz;
    const unsigned short* rWls = rWl + lz;

    // xf store (reads current state; no writes to xu this phase)
    {
      int r = tid >> 6, cc0 = (tid & 63) * 2;
      long row = ((long)(b0 + r) * len + tc) * 128 + cc0;
      *(unsigned int*)(xfh + row) =
          (unsigned int)xu_h[r][cc0] | ((unsigned int)xu_h[r][cc0 + 1] << 16);
      *(unsigned int*)(xfl + row) =
          (unsigned int)xu_l[r][cc0] | ((unsigned int)xu_l[r][cc0 + 1] << 16);
    }
    // G1: xu pair x W1 (hi regs, lo stream) -> h1 pair; coltile = w
    {
      f4v p = zero4(), q = zero4();
#pragma unroll
      for (int kk = 0; kk < 5; ++kk) {
        h8v ah = *(const h8v*)(&xu_h[c][kk * 32 + g * 8]);
        h8v al = *(const h8v*)(&xu_l[c][kk * 32 + g * 8]);
        h8v bl = *(const h8v*)(W1ls + (((long)w * 5 + kk) * 64 + l) * 8);
        p = mfmaH(ah, w1h_r[kk], p);
        q = mfmaH(al, w1h_r[kk], q);
        q = mfmaH(ah, bl, q);
      }
#pragma unroll
      for (int j = 0; j < 4; ++j) {
        float tv = tanhf_fast(p[j] + q[j] * 0x1p-11f + bb);
        _Float16 hi = (_Float16)tv;
        h1h[g * 4 + j][w * 16 + c] = __builtin_bit_cast(unsigned short, hi);
        h1l[g * 4 + j][w * 16 + c] = f2h((tv - (float)hi) * 2048.f);
      }
    }
    __syncthreads();  // A: h1 ready
    // G2: h1 pair x W2 (hi regs, lo stream) -> h2 pair; coltile = w
    {
      f4v p = zero4(), q = zero4(), r2 = zero4();
#pragma unroll
      for (int kk = 0; kk < 8; ++kk) {
        h8v ah = *(const h8v*)(&h1h[c][kk * 32 + g * 8]);
        h8v al = *(const h8v*)(&h1l[c][kk * 32 + g * 8]);
        h8v bl = *(const h8v*)(W2ls + (((long)w * 8 + kk) * 64 + l) * 8);
        p = mfmaH(ah, w2h_r[kk], p);
        q = mfmaH(al, w2h_r[kk], q);
        r2 = mfmaH(ah, bl, r2);
      }
#pragma unroll
      for (int j = 0; j < 4; ++j) {
        float tv = tanhf_fast(p[j] + (q[j] + r2[j]) * 0x1p-11f + cb);
        _Float16 hi = (_Float16)tv;
        h2h[g * 4 + j][w * 16 + c] = __builtin_bit_cast(unsigned short, hi);
        h2l[g * 4 + j][w * 16 + c] = f2h((tv - (float)hi) * 2048.f);
      }
    }
    __syncthreads();  // B: h2 ready
    // G3 split: waves 0-7 h2@W3 (hold partials), waves 8-15 xu@rW -> LDS part
    float pv[4], qv[4];
    if (w < 8) {
      f4v p = zero4(), q = zero4(), r2 = zero4();
#pragma unroll
      for (int kk = 0; kk < 8; ++kk) {
        h8v ah = *(const h8v*)(&h2h[c][kk * 32 + g * 8]);
        h8v al = *(const h8v*)(&h2l[c][kk * 32 + g * 8]);
        h8v bh = *(const h8v*)(&w3h_l[(((long)w * 8 + kk) * 64 + l) * 8]);
        h8v bl = *(const h8v*)(W3ls + (((long)w * 8 + kk) * 64 + l) * 8);
        p = mfmaH(ah, bh, p);
        q = mfmaH(al, bh, q);
        r2 = mfmaH(ah, bl, r2);
      }
#pragma unroll
      for (int j = 0; j < 4; ++j) { pv[j] = p[j]; qv[j] = q[j] + r2[j]; }
    } else {
      const int cw = w - 8;
      f4v p = zero4(), q = zero4();
#pragma unroll
      for (int kk = 0; kk < 5; ++kk) {
        h8v ah = *(const h8v*)(&xu_h[c][kk * 32 + g * 8]);
        h8v al = *(const h8v*)(&xu_l[c][kk * 32 + g * 8]);
        h8v bh = *(const h8v*)(&rwh_l[(((long)cw * 5 + kk) * 64 + l) * 8]);
        h8v bl = *(const h8v*)(rWls + (((long)cw * 5 + kk) * 64 + l) * 8);
        p = mfmaH(ah, bh, p);
        q = mfmaH(al, bh, q);
        q = mfmaH(ah, bl, q);
      }
#pragma unroll
      for (int j = 0; j < 4; ++j)
        part[g * 4 + j][cw * 16 + c] = p[j] + q[j] * 0x1p-11f;
    }
    __syncthreads();  // C: partials ready; all xu reads done
    // D: waves 0-7 combine + state write; waves 8-11 stage u_{t+1}
    if (w < 8) {
#pragma unroll
      for (int j = 0; j < 4; ++j) {
        float xn = pv[j] + qv[j] * 0x1p-11f + part[g * 4 + j][w * 16 + c] + dB;
        _Float16 hi = (_Float16)xn;
        xu_h[g * 4 + j][w * 16 + c] = __builtin_bit_cast(unsigned short, hi);
        xu_l[g * 4 + j][w * 16 + c] = f2h((xn - (float)hi) * 2048.f);
      }
    } else if (w < 12) {
      int idx = (w - 8) * 64 + l;
      int r = idx >> 4, cc = idx & 15;
      int tt = (t + 1 < 256) ? (t + 1) : 255;
      float uv = ufut[((long)(b0 + r) * 256 + tt) * 16 + cc];
      _Float16 hi = (_Float16)uv;
      xu_h[r][128 + cc] = __builtin_bit_cast(unsigned short, hi);
      xu_l[r][128 + cc] = f2h((uv - (float)hi) * 2048.f);
    }
    __syncthreads();  // D: state + u ready for next step
  }
  // chunk-final state writeback (fp32 = hi + lo*2^-11, exact)
  for (int idx = tid; idx < 2048; idx += 1024) {
    int r = idx >> 7, cc = idx & 127;
    xstate[(long)(b0 + r) * 128 + cc] =
        h2f(xu_h[r][cc]) + h2f(xu_l[r][cc]) * 0x1p-11f;
  }
}

// ---------------- output network h (xf pair x f16-single weights) ------------
__global__ __launch_bounds__(512, 2)
void hnet_kernel(const unsigned short* __restrict__ xfh, const unsigned short* __restrict__ xfl,
                 const unsigned short* __restrict__ W1, const unsigned short* __restrict__ W2,
                 const unsigned short* __restrict__ W3, const unsigned short* __restrict__ rW,
                 const float* __restrict__ b1, const float* __restrict__ b2,
                 const float* __restrict__ b3, const float* __restrict__ rb,
                 float* __restrict__ out, int t0, int len) {
  __shared__ __align__(16) unsigned short h1[64][264];
  __shared__ __align__(16) unsigned short h2[64][264];
  __shared__ float part[4][16][16];
  const int tid = threadIdx.x;
  const int w = tid >> 6, l = tid & 63;
  const int c = l & 15, g = l >> 4;
  const long row0 = (long)blockIdx.x * 64;

  {  // stage A: h1 = tanh(xf(pair) @ W1 + b1)
    h8v w1f[2][4];
#pragma unroll
    for (int ct = 0; ct < 2; ++ct)
#pragma unroll
      for (int kk = 0; kk < 4; ++kk)
        w1f[ct][kk] = *(const h8v*)(W1 + (((long)(2 * w + ct) * 4 + kk) * 64 + l) * 8);
    const float bbA = b1[(2 * w + 0) * 16 + c], bbB = b1[(2 * w + 1) * 16 + c];
    for (int rt = 0; rt < 4; ++rt) {
      f4v t10 = zero4(), tl0 = zero4(), t11 = zero4(), tl1 = zero4();
#pragma unroll
      for (int kk = 0; kk < 4; ++kk) {
        h8v ah = *(const h8v*)(xfh + (row0 + rt * 16 + c) * 128 + kk * 32 + g * 8);
        h8v al = *(const h8v*)(xfl + (row0 + rt * 16 + c) * 128 + kk * 32 + g * 8);
        t10 = mfmaH(ah, w1f[0][kk], t10);
        tl0 = mfmaH(al, w1f[0][kk], tl0);
        t11 = mfmaH(ah, w1f[1][kk], t11);
        tl1 = mfmaH(al, w1f[1][kk], tl1);
      }
#pragma unroll
      for (int j = 0; j < 4; ++j) {
        h1[rt * 16 + g * 4 + j][(2 * w + 0) * 16 + c] =
            f2h(tanhf_fast(t10[j] + tl0[j] * 0x1p-11f + bbA));
        h1[rt * 16 + g * 4 + j][(2 * w + 1) * 16 + c] =
            f2h(tanhf_fast(t11[j] + tl1[j] * 0x1p-11f + bbB));
      }
    }
  }
  __syncthreads();
  {  // stage B: h2 = tanh(h1 @ W2 + b2), f16 single
    h8v w2f[2][8];
#pragma unroll
    for (int ct = 0; ct < 2; ++ct)
#pragma unroll
      for (int kk = 0; kk < 8; ++kk)
        w2f[ct][kk] = *(const h8v*)(W2 + (((long)(2 * w + ct) * 8 + kk) * 64 + l) * 8);
    const float bbA = b2[(2 * w + 0) * 16 + c], bbB = b2[(2 * w + 1) * 16 + c];
    for (int rt = 0; rt < 4; ++rt) {
      f4v a0 = zero4(), a1 = zero4();
#pragma unroll
      for (int kk = 0; kk < 8; ++kk) {
        h8v a = *(const h8v*)(&h1[rt * 16 + c][kk * 32 + g * 8]);
        a0 = mfmaH(a, w2f[0][kk], a0);
        a1 = mfmaH(a, w2f[1][kk], a1);
      }
#pragma unroll
      for (int j = 0; j < 4; ++j) {
        h2[rt * 16 + g * 4 + j][(2 * w + 0) * 16 + c] = f2h(tanhf_fast(a0[j] + bbA));
        h2[rt * 16 + g * 4 + j][(2 * w + 1) * 16 + c] = f2h(tanhf_fast(a1[j] + bbB));
      }
    }
  }
  __syncthreads();
  {  // stage C: y = h2 @ W3 + xf(pair) @ rW + b3 + rb
    const int rt = w & 3, kh = w >> 2;
    f4v t1 = zero4(), tl = zero4();
#pragma unroll
    for (int kk = 0; kk < 4; ++kk) {
      const int kkg = kh * 4 + kk;
      h8v a = *(const h8v*)(&h2[rt * 16 + c][kkg * 32 + g * 8]);
      h8v b = *(const h8v*)(W3 + ((long)(kkg * 64 + l)) * 8);
      t1 = mfmaH(a, b, t1);
    }
#pragma unroll
    for (int kk = 0; kk < 2; ++kk) {
      const int kkg = kh * 2 + kk;
      h8v ah = *(const h8v*)(xfh + (row0 + rt * 16 + c) * 128 + kkg * 32 + g * 8);
      h8v al = *(const h8v*)(xfl + (row0 + rt * 16 + c) * 128 + kkg * 32 + g * 8);
      h8v b = *(const h8v*)(rW + ((long)(kkg * 64 + l)) * 8);
      t1 = mfmaH(ah, b, t1);
      tl = mfmaH(al, b, tl);
    }
    float val[4];
#pragma unroll
    for (int j = 0; j < 4; ++j) val[j] = t1[j] + tl[j] * 0x1p-11f;
    if (w >= 4) {
#pragma unroll
      for (int j = 0; j < 4; ++j) part[rt][g * 4 + j][c] = val[j];
    }
    __syncthreads();
    if (w < 4) {
      const float bias = b3[c] + rb[c];
#pragma unroll
      for (int j = 0; j < 4; ++j) {
        const long grow = row0 + rt * 16 + g * 4 + j;
        const long bq = grow / len;
        const int tq = (int)(grow - bq * len);
        out[(bq * 256 + (t0 + tq)) * 16 + c] = val[j] + part[rt][g * 4 + j][c] + bias;
      }
    }
  }
}

// ---------------- host -------------------------------------------------------
extern "C" void kernel_launch(void* const* d_in, const int* in_sizes, int n_in,
                              void* d_out, int out_size, void* d_ws, size_t ws_size,
                              hipStream_t stream) {
  (void)in_sizes; (void)n_in; (void)out_size;
  const float* upast = (const float*)d_in[0];
  const float* ypast = (const float*)d_in[1];
  const float* ufut  = (const float*)d_in[2];
  const float* e_rW = (const float*)d_in[3];
  const float* e_rb = (const float*)d_in[4];
  const float* e_W1 = (const float*)d_in[5];
  const float* e_b1 = (const float*)d_in[6];
  const float* e_W2 = (const float*)d_in[7];
  const float* e_b2 = (const float*)d_in[8];
  const float* e_W3 = (const float*)d_in[9];
  const float* e_b3 = (const float*)d_in[10];
  const float* f_rW = (const float*)d_in[11];
  const float* f_rb = (const float*)d_in[12];
  const float* f_W1 = (const float*)d_in[13];
  const float* f_b1 = (const float*)d_in[14];
  const float* f_W2 = (const float*)d_in[15];
  const float* f_b2 = (const float*)d_in[16];
  const float* f_W3 = (const float*)d_in[17];
  const float* f_b3 = (const float*)d_in[18];
  const float* h_rW = (const float*)d_in[19];
  const float* h_rb = (const float*)d_in[20];
  const float* h_W1 = (const float*)d_in[21];
  const float* h_b1 = (const float*)d_in[22];
  const float* h_W2 = (const float*)d_in[23];
  const float* h_b2 = (const float*)d_in[24];
  const float* h_W3 = (const float*)d_in[25];
  const float* h_b3 = (const float*)d_in[26];
  float* out = (float*)d_out;

  // swizzle table: e_* bf16 pair (mode0), f_* f16 pair (mode3), h_* f16 (mode1)
  const float* srcs[12] = { e_W1, e_W2, e_W3, e_rW, f_W1, f_W2, f_W3, f_rW,
                            h_W1, h_W2, h_W3, h_rW };
  const int Ks [12] = {1024, 256, 256, 1024, 144, 256, 256, 144, 128, 256, 256, 128};
  const int Kps[12] = {1024, 256, 256, 1024, 160, 256, 256, 160, 128, 256, 256, 128};
  const int Ns [12] = { 256, 256, 128,  128, 256, 256, 128, 128, 256, 256,  16,  16};
  const int modes[12] = {0,0,0,0, 3,3,3,3, 1,1,1,1};

  SwzTable tbl;
  long woff = 0, offs[12];
  for (int i = 0; i < 12; ++i) { offs[i] = woff; woff += (long)Kps[i] * Ns[i]; }
  const long EA = offs[4];              // e-region elems
  const long FB = 2 * EA;
  const long EB = offs[8] - offs[4];    // f-region elems
  const long HB = FB + 2 * EB;
  for (int i = 0; i < 12; ++i) {
    tbl.d[i].src = srcs[i]; tbl.d[i].woff = offs[i];
    tbl.d[i].K = Ks[i]; tbl.d[i].Kp = Kps[i]; tbl.d[i].N = Ns[i]; tbl.d[i].mode = modes[i];
    if (modes[i] == 0)      { tbl.d[i].dhi = offs[i];              tbl.d[i].dlo = EA + offs[i]; }
    else if (modes[i] == 3) { long lo = offs[i] - offs[4];
                              tbl.d[i].dhi = FB + lo;              tbl.d[i].dlo = FB + EB + lo; }
    else                    { long lo = offs[i] - offs[8];
                              tbl.d[i].dhi = HB + lo;              tbl.d[i].dlo = 0; }
  }
  tbl.tot_work = woff;

  unsigned short* wswz = (unsigned short*)d_ws;
  const long WSHORTS = HB + (offs[11] - offs[8]) + (long)Kps[11] * Ns[11];
  const size_t XOFF = ((size_t)WSHORTS * 2 + 4095) & ~(size_t)4095;
  float* xstate = (float*)((char*)d_ws + XOFF);
  const size_t XF0 = XOFF + (2u << 20);
  int c = 64;
  {
    long cmax = ((long)ws_size - (long)XF0) >> 21;  // 2 MB per time-step (pair)
    if (cmax < c) c = (int)cmax;
    if (c < 1) c = 1;
  }
  unsigned short* xfh = (unsigned short*)((char*)d_ws + XF0);
  unsigned short* xfl = (unsigned short*)((char*)d_ws + XF0 + (size_t)c * 1048576);

  // kernel weight pointers
  const unsigned short* eW1h = wswz + offs[0];          const unsigned short* eW1l = wswz + EA + offs[0];
  const unsigned short* eW2h = wswz + offs[1];          const unsigned short* eW2l = wswz + EA + offs[1];
  const unsigned short* eW3h = wswz + offs[2];          const unsigned short* eW3l = wswz + EA + offs[2];
  const unsigned short* erWh = wswz + offs[3];          const unsigned short* erWl = wswz + EA + offs[3];
  const unsigned short* fW1h = wswz + FB + 0;           const unsigned short* fW1l = wswz + FB + EB + 0;
  const unsigned short* fW2h = wswz + FB + 40960;       const unsigned short* fW2l = wswz + FB + EB + 40960;
  const unsigned short* fW3h = wswz + FB + 106496;      const unsigned short* fW3l = wswz + FB + EB + 106496;
  const unsigned short* frWh = wswz + FB + 139264;      const unsigned short* frWl = wswz + FB + EB + 139264;
  const unsigned short* hW1 = wswz + HB + 0;
  const unsigned short* hW2 = wswz + HB + 32768;
  const unsigned short* hW3 = wswz + HB + 98304;
  const unsigned short* hrW = wswz + HB + 102400;

  swz_kernel<<<(int)((tbl.tot_work + 255) / 256), 256, 0, stream>>>(tbl, wswz);
  enc_kernel<<<256, 512, 0, stream>>>(upast, ypast,
                                      eW1h, eW1l, eW2h, eW2l, eW3h, eW3l, erWh, erWl,
                                      e_b1, e_b2, e_b3, e_rb, xstate);
  for (int t0 = 0; t0 < 256; t0 += c) {
    int len = 256 - t0; if (len > c) len = c;
    recur_kernel<<<256, 1024, 0, stream>>>(ufut, fW1h, fW1l, fW2h, fW2l, fW3h, fW3l,
                                           frWh, frWl, f_b1, f_b2, f_b3, f_rb,
                                           xstate, xfh, xfl, t0, len);
    hnet_kernel<<<64 * len, 512, 0, stream>>>(xfh, xfl, hW1, hW2, hW3, hrW,
                                              h_b1, h_b2, h_b3, h_rb, out, t0, len);
  }
}